// Round 13
// baseline (341.837 us; speedup 1.0000x reference)
//
#include <hip/hip_runtime.h>

typedef unsigned short u16;
typedef unsigned int u32;
typedef __attribute__((ext_vector_type(8))) __bf16 bf16x8;
typedef __attribute__((ext_vector_type(4))) float f32x4;
typedef __attribute__((ext_vector_type(16))) float f32x16;
typedef __attribute__((ext_vector_type(4))) unsigned short u16x4;
typedef __attribute__((ext_vector_type(8))) unsigned short u16x8;
typedef __attribute__((ext_vector_type(2))) int i32x2;

#define LOG2E 1.44269504088896340736f

__device__ __forceinline__ u16 f2bf(float f) {
  union { float f; unsigned u; } c; c.f = f;
  unsigned r = c.u + 0x7FFFu + ((c.u >> 16) & 1u);
  return (u16)(r >> 16);
}
__device__ __forceinline__ float bf2f(u16 h) {
  union { unsigned u; float f; } c; c.u = ((unsigned)h) << 16;
  return c.f;
}
__device__ __forceinline__ float max3f(float a, float b, float c) {
  return fmaxf(fmaxf(a, b), c);
}

__device__ __forceinline__ void gload_lds16(const u16* g, u16* l) {
  __builtin_amdgcn_global_load_lds((const __attribute__((address_space(1))) unsigned int*)g,
                                   (__attribute__((address_space(3))) unsigned int*)l, 16, 0, 0);
}

// XCD-chunked block remap (T1). Requires nwg % 8 == 0.
__device__ __forceinline__ void xcd_remap(int& bn, int& bm, int& bz) {
  int gx = gridDim.x, gxy = gridDim.x * gridDim.y;
  int lin = blockIdx.z * gxy + blockIdx.y * gx + blockIdx.x;
  int nwg = gxy * gridDim.z;
  int q = nwg >> 3;
  int w = (lin & 7) * q + (lin >> 3);
  bz = w / gxy;
  int rem = w - bz * gxy;
  bm = rem / gx;
  bn = rem - bm * gx;
}

// fast exact GELU: erf via Abramowitz-Stegun 7.1.26 (|eps| <= 1.5e-7)
__device__ __forceinline__ float gelu_fast(float x) {
  float z = fabsf(x) * 0.70710678118654752f;
  float t = 1.0f / (1.0f + 0.3275911f * z);
  float poly = t * (0.254829592f + t * (-0.284496736f + t * (1.421413741f +
               t * (-1.453152027f + t * 1.061405429f))));
  float e = __builtin_amdgcn_exp2f(-z * z * LOG2E);
  float erfz = 1.0f - poly * e;
  float s = (x >= 0.0f) ? erfz : -erfz;
  return 0.5f * x * (1.0f + s);
}

// ---------------- fused f32 -> bf16 conversion (all 9 tensors, one launch) ----------------
__global__ __launch_bounds__(256) void cvt_all(
    const float* __restrict__ s0, const float* __restrict__ s1, const float* __restrict__ s2,
    const float* __restrict__ s3, const float* __restrict__ s4, const float* __restrict__ s5,
    const float* __restrict__ s6, const float* __restrict__ s7, const float* __restrict__ s8,
    u16* __restrict__ d0, u16* __restrict__ d1, u16* __restrict__ d2,
    u16* __restrict__ d3, u16* __restrict__ d4, u16* __restrict__ d5,
    u16* __restrict__ d6, u16* __restrict__ d7, u16* __restrict__ d8) {
  int i = blockIdx.x * 256 + threadIdx.x;
  if (i >= 6291456) return;
  const float* src; u16* dst; int off;
  if (i < 3145728) {
    if (i < 1048576)      { src = s0; dst = d0; off = 0; }
    else if (i < 2097152) { src = s1; dst = d1; off = 1048576; }
    else                  { src = s2; dst = d2; off = 2097152; }
  } else if (i < 4194304) {
    if (i < 3407872)      { src = s3; dst = d3; off = 3145728; }
    else if (i < 3670016) { src = s4; dst = d4; off = 3407872; }
    else if (i < 3932160) { src = s5; dst = d5; off = 3670016; }
    else                  { src = s6; dst = d6; off = 3932160; }
  } else {
    if (i < 5242880)      { src = s7; dst = d7; off = 4194304; }
    else                  { src = s8; dst = d8; off = 5242880; }
  }
  int j = i - off;
  f32x4 v = ((const f32x4*)src)[j];
  u16x4 o;
  o[0] = f2bf(v[0]); o[1] = f2bf(v[1]); o[2] = f2bf(v[2]); o[3] = f2bf(v[3]);
  ((u16x4*)dst)[j] = o;
}

// ---------------- mask expansion (bool/int32 autodetect) ----------------
__global__ void build_masks(const void* __restrict__ pm, float* __restrict__ maskbias,
                            float* __restrict__ qmask, int n) {
  __shared__ int sflag;
  if (threadIdx.x == 0) sflag = 0;
  __syncthreads();
  const unsigned* pw = (const unsigned*)pm;
  int nwords = n / 4;
  int local = 0;
  for (int i = threadIdx.x; i < nwords; i += blockDim.x)
    if (pw[i] > 1u) local = 1;
  if (local) atomicOr(&sflag, 1);
  __syncthreads();
  bool isbool = (sflag != 0);
  for (int i = threadIdx.x; i < n; i += blockDim.x) {
    int m = isbool ? (int)((const unsigned char*)pm)[i] : ((const int*)pm)[i];
    maskbias[i] = m ? 0.0f : -2e30f;
    qmask[i]    = m ? 1.0f : 0.0f;
  }
}

// ---------------- GEMM core v6: 4 waves x (64x64), BK=32 2-buf issue-early, 3 blk/CU ------
template<int EPI>
__device__ __forceinline__ void gemm_core(const u16* __restrict__ A, const u16* __restrict__ Bw,
                                          const float* __restrict__ bias, u16* __restrict__ C,
                                          int N, int Kstride, int Klen, int bn, int bm, int tid) {
  __shared__ u16 smem[2][8192];
  int wave = tid >> 6, lane = tid & 63;
  int l15 = lane & 15, l4 = lane >> 4;
  int wr = (wave >> 1) * 64, wc = (wave & 1) * 64;
  int mrow0 = bm * 128, ncol0 = bn * 128;
  int srow = lane >> 2;
  int scol = (lane & 3) * 8;

  const u16* asrc0 = A  + (size_t)(mrow0 + (wave * 2 + 0) * 16 + srow) * Kstride + scol;
  const u16* asrc1 = A  + (size_t)(mrow0 + (wave * 2 + 1) * 16 + srow) * Kstride + scol;
  const u16* bsrc0 = Bw + (size_t)(ncol0 + (wave * 2 + 0) * 16 + srow) * Kstride + scol;
  const u16* bsrc1 = Bw + (size_t)(ncol0 + (wave * 2 + 1) * 16 + srow) * Kstride + scol;
  u16* ad0 = &smem[0][(wave * 2 + 0) * 512];
  u16* ad1 = &smem[0][(wave * 2 + 1) * 512];
  u16* bd0 = &smem[0][4096 + (wave * 2 + 0) * 512];
  u16* bd1 = &smem[0][4096 + (wave * 2 + 1) * 512];

  auto stage = [&](int buf, int k0) {
    gload_lds16(asrc0 + k0, ad0 + buf * 8192);
    gload_lds16(asrc1 + k0, ad1 + buf * 8192);
    gload_lds16(bsrc0 + k0, bd0 + buf * 8192);
    gload_lds16(bsrc1 + k0, bd1 + buf * 8192);
  };

  f32x4 acc[4][4];
#pragma unroll
  for (int i = 0; i < 4; i++)
#pragma unroll
    for (int j = 0; j < 4; j++) acc[i][j] = (f32x4)0.0f;

  int nsteps = Klen >> 5;
  stage(0, 0);
  for (int s = 0; s < nsteps; s++) {
    asm volatile("s_waitcnt vmcnt(0)" ::: "memory");
    __builtin_amdgcn_s_barrier();
    if (s + 1 < nsteps) stage((s + 1) & 1, (s + 1) << 5);
    const u16* as = &smem[s & 1][0];
    const u16* bs = &smem[s & 1][4096];
    bf16x8 af[4], bfr[4];
#pragma unroll
    for (int mi = 0; mi < 4; mi++) af[mi]  = *(const bf16x8*)(as + (wr + mi * 16 + l15) * 32 + l4 * 8);
#pragma unroll
    for (int ni = 0; ni < 4; ni++) bfr[ni] = *(const bf16x8*)(bs + (wc + ni * 16 + l15) * 32 + l4 * 8);
#pragma unroll
    for (int mi = 0; mi < 4; mi++)
#pragma unroll
      for (int ni = 0; ni < 4; ni++)
        acc[mi][ni] = __builtin_amdgcn_mfma_f32_16x16x32_bf16(af[mi], bfr[ni], acc[mi][ni], 0, 0, 0);
  }

  __syncthreads();
  u16* ct = &smem[0][0];
#pragma unroll
  for (int p = 0; p < 2; p++) {
    if (p) __syncthreads();
    if ((wave >> 1) == p) {
#pragma unroll
      for (int ni = 0; ni < 4; ni++) {
        int gcol = ncol0 + wc + ni * 16 + l15;
        float bv = (EPI > 0) ? bias[gcol] : 0.0f;
#pragma unroll
        for (int mi = 0; mi < 4; mi++) {
#pragma unroll
          for (int r = 0; r < 4; r++) {
            float v = acc[mi][ni][r] + bv;
            if (EPI == 2) v = gelu_fast(v);
            ct[(mi * 16 + l4 * 4 + r) * 136 + wc + ni * 16 + l15] = f2bf(v);
          }
        }
      }
    }
    __syncthreads();
    int lrow = tid >> 2, cq = tid & 3;
#pragma unroll
    for (int j = 0; j < 4; j++) {
      int col = cq * 8 + j * 32;
      u16x8 vv = *(const u16x8*)(ct + lrow * 136 + col);
      *(u16x8*)(C + (size_t)(mrow0 + p * 64 + lrow) * N + ncol0 + col) = vv;
    }
  }
}

template<int EPI>
__global__ __launch_bounds__(256, 3) void gemm_bt(const u16* __restrict__ A, const u16* __restrict__ Bw,
                                                  const float* __restrict__ bias, u16* __restrict__ C,
                                                  int N, int K) {
  int bn, bm, bz;
  xcd_remap(bn, bm, bz);
  gemm_core<EPI>(A, Bw, bias, C, N, K, K, bn, bm, threadIdx.x);
}

__global__ __launch_bounds__(256, 3) void gemm_splitk(const u16* __restrict__ A, const u16* __restrict__ Bw,
                                                      u16* __restrict__ P, int N, int Kstride, int Kc) {
  int bn, bm, bz;
  xcd_remap(bn, bm, bz);
  size_t M = (size_t)gridDim.y * 128;
  gemm_core<0>(A + (size_t)bz * Kc, Bw + (size_t)bz * Kc, nullptr,
               P + (size_t)bz * M * N, N, Kstride, Kc, bn, bm, threadIdx.x);
}

__global__ __launch_bounds__(256, 3) void gemm_qkv(const u16* __restrict__ qb, const u16* __restrict__ kb,
                                                   const u16* __restrict__ vb,
                                                   const u16* __restrict__ wq, const u16* __restrict__ wk,
                                                   const u16* __restrict__ wv,
                                                   u16* __restrict__ Qo, u16* __restrict__ Ko, u16* __restrict__ Vo) {
  int bn, bm, bz;
  xcd_remap(bn, bm, bz);
  const u16* A; const u16* W; u16* C;
  if (bz == 0)      { A = qb; W = wq; C = Qo; }
  else if (bz == 1) { A = kb; W = wk; C = Ko; }
  else              { A = vb; W = wv; C = Vo; }
  gemm_core<0>(A, W, nullptr, C, 1024, 1024, 1024, bn, bm, threadIdx.x);
}

// ---------------- GEMM 8-phase 256^2 (m201 template port) for FFN1 -----------------------
// Same schedule as round 11; epilogue P-loop now force-unrolled so every acc index is
// compile-time (rule #20 — the rolled loop put acc[] in scratch: 164 MB WRITE_SIZE).
__global__ __launch_bounds__(512, 2) void gemm_8ph(const u16* __restrict__ A, const u16* __restrict__ Bw,
                                                   const float* __restrict__ bias, u16* __restrict__ C,
                                                   int N, int K) {
  __shared__ u16 smem[65536];   // 128 KB: per buf 32768 u16 = [Ah0|Ah1|Bh0|Bh1] x 8192
  int bn, bm, bz;
  xcd_remap(bn, bm, bz);
  const int tid = threadIdx.x, w = tid >> 6, l = tid & 63;
  const int wm = w >> 2, wn = w & 3;
  const int l15 = l & 15, l4 = l >> 4;
  const int mrow0 = bm * 256, ncol0 = bn * 256;
  const int nt = K >> 6;

  const int rl = l >> 3;
  const int osw = ((l & 7) * 16) ^ (rl << 4);
  const u16* aBase = A  + (size_t)(mrow0 + w * 16 + rl) * K + (osw >> 1);
  const u16* bBase = Bw + (size_t)(ncol0 + w * 16 + rl) * K + (osw >> 1);

  auto stA = [&](int buf, int half, int jj) {
    const u16* s = aBase + (size_t)(half * 128) * K + jj * 64;
    u16* d = smem + buf * 32768 + half * 8192 + w * 1024;
    gload_lds16(s, d);
    gload_lds16(s + (size_t)8 * K, d + 512);
  };
  auto stB = [&](int buf, int half, int jj) {
    const u16* s = bBase + (size_t)(half * 128) * K + jj * 64;
    u16* d = smem + 16384 + buf * 32768 + half * 8192 + w * 1024;
    gload_lds16(s, d);
    gload_lds16(s + (size_t)8 * K, d + 512);
  };

  const char* smc = (const char*)smem;
  const int kb0 = l4 * 16;
  const int aswz = (l15 & 7) << 4;
  auto rdA = [&](int buf, int p, int rf, int kk) -> bf16x8 {
    int lr = p * 32 + rf * 16 + l15;
    return *(const bf16x8*)(smc + buf * 65536 + wm * 16384 + lr * 128 + ((kk * 64 + kb0) ^ aswz));
  };
  auto rdB = [&](int buf, int cf, int kk) -> bf16x8 {
    int lc = (wn & 1) * 64 + cf * 16 + l15;
    return *(const bf16x8*)(smc + buf * 65536 + 32768 + (wn >> 1) * 16384 + lc * 128 + ((kk * 64 + kb0) ^ aswz));
  };

  f32x4 acc[8][4];
#pragma unroll
  for (int i = 0; i < 8; i++)
#pragma unroll
    for (int j = 0; j < 4; j++) acc[i][j] = (f32x4)0.0f;

  stB(0, 0, 0); stB(0, 1, 0); stA(0, 0, 0); stA(0, 1, 0);
  stB(1, 0, 1); stB(1, 1, 1);
  asm volatile("s_waitcnt vmcnt(4)" ::: "memory");
  asm volatile("s_barrier" ::: "memory");

  for (int j = 0; j < nt; j++) {
    int buf = j & 1, nb = buf ^ 1;
    bf16x8 bfr[4][2];
    bf16x8 af[2][2];
    // ---- phase 0: read all B + A q0; stage (j+1).Ah0
#pragma unroll
    for (int cf = 0; cf < 4; cf++) { bfr[cf][0] = rdB(buf, cf, 0); bfr[cf][1] = rdB(buf, cf, 1); }
#pragma unroll
    for (int rf = 0; rf < 2; rf++) { af[rf][0] = rdA(buf, 0, rf, 0); af[rf][1] = rdA(buf, 0, rf, 1); }
    if (j + 1 < nt) stA(nb, 0, j + 1);
    asm volatile("s_barrier" ::: "memory");
    __builtin_amdgcn_s_setprio(1);
#pragma unroll
    for (int kk = 0; kk < 2; kk++)
#pragma unroll
      for (int rf = 0; rf < 2; rf++)
#pragma unroll
        for (int cf = 0; cf < 4; cf++)
          acc[rf][cf] = __builtin_amdgcn_mfma_f32_16x16x32_bf16(af[rf][kk], bfr[cf][kk], acc[rf][cf], 0, 0, 0);
    __builtin_amdgcn_s_setprio(0);
    asm volatile("s_barrier" ::: "memory");
    // ---- phase 1: A q1; stage (j+1).Ah1
#pragma unroll
    for (int rf = 0; rf < 2; rf++) { af[rf][0] = rdA(buf, 1, rf, 0); af[rf][1] = rdA(buf, 1, rf, 1); }
    if (j + 1 < nt) stA(nb, 1, j + 1);
    asm volatile("s_barrier" ::: "memory");
    __builtin_amdgcn_s_setprio(1);
#pragma unroll
    for (int kk = 0; kk < 2; kk++)
#pragma unroll
      for (int rf = 0; rf < 2; rf++)
#pragma unroll
        for (int cf = 0; cf < 4; cf++)
          acc[2 + rf][cf] = __builtin_amdgcn_mfma_f32_16x16x32_bf16(af[rf][kk], bfr[cf][kk], acc[2 + rf][cf], 0, 0, 0);
    __builtin_amdgcn_s_setprio(0);
    asm volatile("s_barrier" ::: "memory");
    // ---- phase 2: A q2; stage (j+2).Bh0
#pragma unroll
    for (int rf = 0; rf < 2; rf++) { af[rf][0] = rdA(buf, 2, rf, 0); af[rf][1] = rdA(buf, 2, rf, 1); }
    if (j + 2 < nt) stB(buf, 0, j + 2);
    asm volatile("s_barrier" ::: "memory");
    __builtin_amdgcn_s_setprio(1);
#pragma unroll
    for (int kk = 0; kk < 2; kk++)
#pragma unroll
      for (int rf = 0; rf < 2; rf++)
#pragma unroll
        for (int cf = 0; cf < 4; cf++)
          acc[4 + rf][cf] = __builtin_amdgcn_mfma_f32_16x16x32_bf16(af[rf][kk], bfr[cf][kk], acc[4 + rf][cf], 0, 0, 0);
    __builtin_amdgcn_s_setprio(0);
    asm volatile("s_barrier" ::: "memory");
    // ---- phase 3: A q3; stage (j+2).Bh1
#pragma unroll
    for (int rf = 0; rf < 2; rf++) { af[rf][0] = rdA(buf, 3, rf, 0); af[rf][1] = rdA(buf, 3, rf, 1); }
    if (j + 2 < nt) stB(buf, 1, j + 2);
    asm volatile("s_barrier" ::: "memory");
    __builtin_amdgcn_s_setprio(1);
#pragma unroll
    for (int kk = 0; kk < 2; kk++)
#pragma unroll
      for (int rf = 0; rf < 2; rf++)
#pragma unroll
        for (int cf = 0; cf < 4; cf++)
          acc[6 + rf][cf] = __builtin_amdgcn_mfma_f32_16x16x32_bf16(af[rf][kk], bfr[cf][kk], acc[6 + rf][cf], 0, 0, 0);
    __builtin_amdgcn_s_setprio(0);
    if (j + 2 < nt)      { asm volatile("s_waitcnt vmcnt(4)" ::: "memory"); }
    else if (j + 1 < nt) { asm volatile("s_waitcnt vmcnt(0)" ::: "memory"); }
    asm volatile("s_barrier" ::: "memory");
  }

  // epilogue: 4 passes of [64 rows][264] LDS bounce -> coalesced u16x8 stores
  // FORCE-UNROLLED: P must be compile-time so acc[] stays in registers (rule #20).
  __syncthreads();
  u16* ct = smem;
  float bv[4];
#pragma unroll
  for (int cf = 0; cf < 4; cf++) bv[cf] = bias[ncol0 + wn * 64 + cf * 16 + l15];
#pragma unroll
  for (int P = 0; P < 4; P++) {
    if (P) __syncthreads();
    if (wm == (P >> 1)) {
#pragma unroll
      for (int q = 0; q < 2; q++)
#pragma unroll
        for (int rf = 0; rf < 2; rf++)
#pragma unroll
          for (int cf = 0; cf < 4; cf++)
#pragma unroll
            for (int r = 0; r < 4; r++) {
              int a = (P & 1) * 4 + q * 2 + rf;
              float v = gelu_fast(acc[a][cf][r] + bv[cf]);
              ct[(q * 32 + rf * 16 + l4 * 4 + r) * 264 + wn * 64 + cf * 16 + l15] = f2bf(v);
            }
    }
    __syncthreads();
#pragma unroll
    for (int it = 0; it < 4; it++) {
      int idx = it * 512 + tid;
      int row = idx >> 5, ch = idx & 31;
      u16x8 vv = *(const u16x8*)(ct + row * 264 + ch * 8);
      *(u16x8*)(C + (size_t)(mrow0 + P * 64 + row) * N + ncol0 + ch * 8) = vv;
    }
  }
}

// ---------------- V transpose: [32][2048][64] -> [32][64][2048] ----------------
__global__ __launch_bounds__(256) void transpose64(const u16* __restrict__ in, u16* __restrict__ out) {
  int bh = blockIdx.y, tb = blockIdx.x;
  __shared__ u16 tile[64 * 72];
  int tid = threadIdx.x;
#pragma unroll
  for (int it = 0; it < 2; it++) {
    int idx = it * 256 + tid;
    int r = idx >> 3, c8 = (idx & 7) * 8;
    u16x8 v = *(const u16x8*)(in + ((size_t)bh * 2048 + tb * 64 + r) * 64 + c8);
    int byte = ((r * 72 + c8) * 2) ^ (((r >> 3) & 7) << 4);
    *(u16x8*)((char*)tile + byte) = v;
  }
  __syncthreads();
#pragma unroll
  for (int it = 0; it < 2; it++) {
    int idx = it * 256 + tid;
    int d = idx >> 3, t8 = (idx & 7) * 8;
    u16x8 o;
#pragma unroll
    for (int e = 0; e < 8; e++) {
      int t = t8 + e;
      int byte = ((t * 72 + d) * 2) ^ (((t >> 3) & 7) << 4);
      o[e] = *(const u16*)((const char*)tile + byte);
    }
    *(u16x8*)(out + ((size_t)bh * 64 + d) * 2048 + tb * 64 + t8) = o;
  }
}

// ---------------- flash attention v5: LDS K/V, swapped-QK, permlane softmax ----------------
__global__ __launch_bounds__(256, 4) void attn4(const u16* __restrict__ Q, const u16* __restrict__ Kg,
                                                const u16* __restrict__ VT,
                                                const float* __restrict__ maskbias,
                                                u16* __restrict__ O0, u16* __restrict__ O1,
                                                float* __restrict__ Ms, float* __restrict__ Ss) {
  const int T = 2048;
  int bh = blockIdx.x;
  int qt = blockIdx.y;
  int sp = blockIdx.z;
  int b = bh >> 4;
  const u16* Qh = Q  + (size_t)bh * T * 64;
  const u16* Kh = Kg + (size_t)bh * T * 64;
  const u16* Vh = VT + (size_t)bh * T * 64;
  u16* Oh = (sp ? O1 : O0) + (size_t)bh * T * 64;
  const float* mb = maskbias + b * T + sp * 1024;
  int tid = threadIdx.x, w = tid >> 6, l = tid & 63;
  int q32 = l & 31, h = l >> 5;
  int qbase = qt * 128 + w * 32;
  const float C = 0.125f * LOG2E;

  __shared__ u16 Ks[2][4096];
  __shared__ u16 Vs[2][4096];

  bf16x8 qf[4];
#pragma unroll
  for (int dc = 0; dc < 4; dc++)
    qf[dc] = *(const bf16x8*)(Qh + (size_t)(qbase + q32) * 64 + dc * 16 + h * 8);

  int rl = l >> 3, ob = (l & 7) * 16;
  int osw = ob ^ (rl << 4);
  int r0 = w * 16 + rl, r1 = w * 16 + 8 + rl;
  const u16* pK0 = Kh + (size_t)(sp * 1024 + r0) * 64 + (osw >> 1);
  const u16* pK1 = Kh + (size_t)(sp * 1024 + r1) * 64 + (osw >> 1);
  const u16* pV0 = Vh + (size_t)r0 * 2048 + sp * 1024 + (osw >> 1);
  const u16* pV1 = Vh + (size_t)r1 * 2048 + sp * 1024 + (osw >> 1);
  u16* dK0 = &Ks[0][0] + (w * 16) * 64;
  u16* dK1 = &Ks[0][0] + (w * 16 + 8) * 64;
  u16* dV0 = &Vs[0][0] + (w * 16) * 64;
  u16* dV1 = &Vs[0][0] + (w * 16 + 8) * 64;

  auto stage = [&](int buf) {
    gload_lds16(pK0, dK0 + buf * 4096);
    gload_lds16(pK1, dK1 + buf * 4096);
    gload_lds16(pV0, dV0 + buf * 4096);
    gload_lds16(pV1, dV1 + buf * 4096);
    pK0 += 4096; pK1 += 4096; pV0 += 64; pV1 += 64;
  };

  f32x16 acc[2];
  acc[0] = (f32x16)0.0f; acc[1] = (f32x16)0.0f;
  float m_ = -3e30f, s_ = 0.0f;

  int swz = (q32 & 7) << 4;

  stage(0);
  for (int t = 0; t < 16; t++) {
    int cur = t & 1;
    __syncthreads();
    if (t < 15) stage(cur ^ 1);
    const char* ksb = (const char*)(&Ks[0][0] + cur * 4096);
    const char* vsb = (const char*)(&Vs[0][0] + cur * 4096);

    bf16x8 kf[2][4];
#pragma unroll
    for (int kvc = 0; kvc < 2; kvc++)
#pragma unroll
      for (int dc = 0; dc < 4; dc++)
        kf[kvc][dc] = *(const bf16x8*)(ksb + (kvc * 32 + q32) * 128 + ((dc * 32 + h * 16) ^ swz));

    f32x16 st[2];
    st[0] = (f32x16)0.0f; st[1] = (f32x16)0.0f;
#pragma unroll
    for (int kvc = 0; kvc < 2; kvc++)
#pragma unroll
      for (int dc = 0; dc < 4; dc++)
        st[kvc] = __builtin_amdgcn_mfma_f32_32x32x16_bf16(kf[kvc][dc], qf[dc], st[kvc], 0, 0, 0);

    float p[32];
#pragma unroll
    for (int kvc = 0; kvc < 2; kvc++) {
#pragma unroll
      for (int g = 0; g < 4; g++) {
        f32x4 mv = *(const f32x4*)(mb + t * 64 + kvc * 32 + g * 8 + h * 4);
#pragma unroll
        for (int r = 0; r < 4; r++)
          p[kvc * 16 + g * 4 + r] = st[kvc][g * 4 + r] * C + mv[r];
      }
    }
    float ma = p[0], mb2 = p[16];
#pragma unroll
    for (int i = 0; i < 7; i++) {
      ma  = max3f(ma,  p[1 + 2 * i],  p[2 + 2 * i]);
      mb2 = max3f(mb2, p[17 + 2 * i], p[18 + 2 * i]);
    }
    ma = fmaxf(ma, p[15]); mb2 = fmaxf(mb2, p[31]);
    float pmax = fmaxf(ma, mb2);
    i32x2 pr = __builtin_amdgcn_permlane32_swap(__float_as_int(pmax), __float_as_int(pmax), false, false);
    pmax = fmaxf(__int_as_float(pr[0]), __int_as_float(pr[1]));

    if (__any(pmax - m_ > 8.0f)) {
      float mnew = fmaxf(m_, pmax);
      float fsc = __builtin_amdgcn_exp2f(m_ - mnew);
      s_ *= fsc;
      m_ = mnew;
#pragma unroll
      for (int g = 0; g < 4; g++)
#pragma unroll
        for (int r = 0; r < 4; r++) {
          float f = __shfl(fsc, g * 8 + h * 4 + r);
          acc[0][g * 4 + r] *= f;
          acc[1][g * 4 + r] *= f;
        }
    }

    float rsum = 0.0f;
    u32 wds[16];
#pragma unroll
    for (int i = 0; i < 16; i++) {
      float a = __builtin_amdgcn_exp2f(p[2 * i] - m_);
      float bq = __builtin_amdgcn_exp2f(p[2 * i + 1] - m_);
      rsum += a + bq;
      union { __bf16 h2[2]; u32 u; } cv;
      cv.h2[0] = (__bf16)a; cv.h2[1] = (__bf16)bq;
      wds[i] = cv.u;
    }
    i32x2 sr = __builtin_amdgcn_permlane32_swap(__float_as_int(rsum), __float_as_int(rsum), false, false);
    rsum = __int_as_float(sr[0]) + __int_as_float(sr[1]);
    s_ += rsum;

#pragma unroll
    for (int kvc = 0; kvc < 2; kvc++) {
      int bse = kvc * 8;
      i32x2 r02 = __builtin_amdgcn_permlane32_swap((int)wds[bse + 0], (int)wds[bse + 2], false, false);
      i32x2 r13 = __builtin_amdgcn_permlane32_swap((int)wds[bse + 1], (int)wds[bse + 3], false, false);
      i32x2 r46 = __builtin_amdgcn_permlane32_swap((int)wds[bse + 4], (int)wds[bse + 6], false, false);
      i32x2 r57 = __builtin_amdgcn_permlane32_swap((int)wds[bse + 5], (int)wds[bse + 7], false, false);
      union { u32 u[4]; bf16x8 v; } pa0, pa1;
      pa0.u[0] = (u32)r02[0]; pa0.u[1] = (u32)r13[0]; pa0.u[2] = (u32)r02[1]; pa0.u[3] = (u32)r13[1];
      pa1.u[0] = (u32)r46[0]; pa1.u[1] = (u32)r57[0]; pa1.u[2] = (u32)r46[1]; pa1.u[3] = (u32)r57[1];
#pragma unroll
      for (int cl = 0; cl < 2; cl++) {
        bf16x8 pa = cl ? pa1.v : pa0.v;
        int cg = kvc * 2 + cl;
#pragma unroll
        for (int dblk = 0; dblk < 2; dblk++) {
          bf16x8 vf = *(const bf16x8*)(vsb + (dblk * 32 + q32) * 128 + ((cg * 32 + h * 16) ^ swz));
          acc[dblk] = __builtin_amdgcn_mfma_f32_32x32x16_bf16(pa, vf, acc[dblk], 0, 0, 0);
        }
      }
    }
  }

#pragma unroll
  for (int g = 0; g < 4; g++) {
#pragma unroll
    for (int r = 0; r < 4; r++) {
      int row = g * 8 + h * 4 + r;
#pragma unroll
      for (int dblk = 0; dblk < 2; dblk++)
        Oh[(size_t)(qbase + row) * 64 + dblk * 32 + q32] = f2bf(acc[dblk][g * 4 + r]);
    }
  }
  if (h == 0) {
    int ro = sp * 65536 + bh * 2048 + qbase + q32;
    Ms[ro] = m_;
    Ss[ro] = s_;
  }
}

// ---------------- split-KV combine (2 splits) ----------------
__global__ __launch_bounds__(256) void attn_combine(const u16* __restrict__ O0, const u16* __restrict__ O1,
                                                    const float* __restrict__ Ms, const float* __restrict__ Ss,
                                                    const float* __restrict__ qmaskf, u16* __restrict__ out) {
  int idx = blockIdx.x * 256 + threadIdx.x;
  int row = idx >> 3;
  int d8 = (idx & 7) * 8;
  int bh = row >> 11, r = row & 2047, b = bh >> 4;
  float m0 = Ms[row], m1 = Ms[65536 + row];
  float mstar = fmaxf(m0, m1);
  float w0 = __builtin_amdgcn_exp2f(m0 - mstar);
  float w1 = __builtin_amdgcn_exp2f(m1 - mstar);
  float den = w0 * Ss[row] + w1 * Ss[65536 + row];
  float scale = qmaskf[b * 2048 + r] / den;
  size_t base = (size_t)row * 64 + d8;
  u16x8 a0 = *(const u16x8*)(O0 + base);
  u16x8 a1 = *(const u16x8*)(O1 + base);
  u16x8 o;
#pragma unroll
  for (int e = 0; e < 8; e++)
    o[e] = f2bf((w0 * bf2f(a0[e]) + w1 * bf2f(a1[e])) * scale);
  *(u16x8*)(out + base) = o;
}

// ---------------- residual + split-K partial sum + (bias) + layernorm ----------------
template<int NP, int A_F32, int ADD_BIAS, int OUT_F32>
__global__ __launch_bounds__(256) void add_ln_multi(const void* __restrict__ Ap,
                                                    const u16* __restrict__ P0, const u16* __restrict__ P1,
                                                    const u16* __restrict__ P2, const u16* __restrict__ P3,
                                                    const float* __restrict__ bias,
                                                    const float* __restrict__ g, const float* __restrict__ be,
                                                    void* __restrict__ outp) {
  int row = blockIdx.x, tid = threadIdx.x;
  int lane = tid & 63, wave = tid >> 6;
  size_t rb = (size_t)row * 1024;
  float x[4];
  if (A_F32) {
    f32x4 a = ((const f32x4*)((const float*)Ap + rb))[tid];
#pragma unroll
    for (int j = 0; j < 4; j++) x[j] = a[j];
  } else {
    u16x4 au = ((const u16x4*)((const u16*)Ap + rb))[tid];
#pragma unroll
    for (int j = 0; j < 4; j++) x[j] = bf2f(au[j]);
  }
  {
    u16x4 p = ((const u16x4*)(P0 + rb))[tid];
#pragma unroll
    for (int j = 0; j < 4; j++) x[j] += bf2f(p[j]);
  }
  if (NP > 1) {
    u16x4 p = ((const u16x4*)(P1 + rb))[tid];
#pragma unroll
    for (int j = 0; j < 4; j++) x[j] += bf2f(p[j]);
  }
  if (NP > 2) {
    u16x4 p = ((const u16x4*)(P2 + rb))[tid];
#pragma unroll
    for (int j = 0; j < 4; j++) x[j] += bf2f(p[j]);
  }
  if (NP > 3) {
    u16x4 p = ((const u16x4*)(P3 + rb))[tid];
#pragma unroll
    for (int j = 0; j < 4; j++) x[j] += bf2f(p[j]);
  }
  if (ADD_BIAS) {
    f32x4 bv = ((const f32x4*)bias)[tid];
#pragma unroll
    for (int j = 0; j < 4; j++) x[j] += bv[j];
  }
  float s = x[0] + x[1] + x[2] + x[3];
  float q = x[0] * x[0] + x[1] * x[1] + x[2] * x[2] + x[3] * x[3];
#pragma unroll
  for (int m = 1; m < 64; m <<= 1) { s += __shfl_xor(s, m); q += __shfl_xor(q, m); }
  __shared__ float rs[4], rq[4];
  if (lane == 0) { rs[wave] = s; rq[wave] = q; }
  __syncthreads();
  float S = rs[0] + rs[1] + rs[2] + rs[3];
  float Qq = rq[0] + rq[1] + rq[2] + rq[3];
  float mean = S * (1.0f / 1024.0f);
  float var = Qq * (1.0f / 1024.0f) - mean * mean;
  float rstd = rsqrtf(var + 1e-5f);
  if (OUT_F32) {
    f32x4 y;
#pragma unroll
    for (int j = 0; j < 4; j++) { int col = tid * 4 + j; y[j] = (x[j] - mean) * rstd * g[col] + be[col]; }
    ((f32x4*)((float*)outp + rb))[tid] = y;
  } else {
    u16x4 y;
#pragma unroll
    for (int j = 0; j < 4; j++) { int col = tid * 4 + j; y[j] = f2bf((x[j] - mean) * rstd * g[col] + be[col]); }
    ((u16x4*)((u16*)outp + rb))[tid] = y;
  }
}

// ---------------- launch ----------------
extern "C" void kernel_launch(void* const* d_in, const int* in_sizes, int n_in,
                              void* d_out, int out_size, void* d_ws, size_t ws_size,
                              hipStream_t stream) {
  const float* q   = (const float*)d_in[0];
  const float* k   = (const float*)d_in[1];
  const float* v   = (const float*)d_in[2];
  const void*  pad = d_in[3];
  const float* Wq  = (const float*)d_in[4];
  const float* Wk  = (const float*)d_in[5];
  const float* Wv  = (const float*)d_in[6];
  const float* Wo  = (const float*)d_in[7];
  const float* W1  = (const float*)d_in[8];
  const float* b1  = (const float*)d_in[9];
  const float* W2  = (const float*)d_in[10];
  const float* b2  = (const float*)d_in[11];
  const float* g1  = (const float*)d_in[12];
  const float* be1 = (const float*)d_in[13];
  const float* g2  = (const float*)d_in[14];
  const float* be2 = (const float*)d_in[15];
  float* out = (float*)d_out;
  char* ws = (char*)d_ws;
  const size_t MB = 1u << 20;

  u16* wq_b = (u16*)(ws + 0 * MB);
  u16* wk_b = (u16*)(ws + 2 * MB);
  u16* wv_b = (u16*)(ws + 4 * MB);
  u16* wo_b = (u16*)(ws + 6 * MB);
  u16* w1_b = (u16*)(ws + 8 * MB);
  u16* w2_b = (u16*)(ws + 16 * MB);
  u16* qb   = (u16*)(ws + 24 * MB);
  u16* kb   = (u16*)(ws + 32 * MB);
  u16* vb   = (u16*)(ws + 40 * MB);
  u16* Qb   = (u16*)(ws + 48 * MB);
  u16* Kb   = (u16*)(ws + 56 * MB);
  u16* Vb   = (u16*)(ws + 64 * MB);
  u16* VTb  = (u16*)(ws + 72 * MB);
  u16* hatt = (u16*)(ws + 80 * MB);
  u16* Op0  = (u16*)(ws + 24 * MB);
  u16* Op1  = (u16*)(ws + 32 * MB);
  float* Ms = (float*)(ws + 88 * MB);
  float* Ss = (float*)(ws + 89 * MB);
  u16* WP   = (u16*)(ws + 40 * MB);
  u16* h1b  = (u16*)(ws + 24 * MB);
  u16* ff1  = (u16*)(ws + 32 * MB);
  u16* Fp   = (u16*)(ws + 64 * MB);
  float* maskbias = (float*)(ws + 96 * MB);
  float* qmaskf   = (float*)(ws + 96 * MB + 16384);

  build_masks<<<1, 256, 0, stream>>>(pad, maskbias, qmaskf, in_sizes[3]);

  cvt_all<<<24576, 256, 0, stream>>>(q, k, v, Wq, Wk, Wv, Wo, W1, W2,
                                     qb, kb, vb, wq_b, wk_b, wv_b, wo_b, w1_b, w2_b);

  gemm_qkv<<<dim3(8, 32, 3), 256, 0, stream>>>(qb, kb, vb, wq_b, wk_b, wv_b, Qb, Kb, Vb);

  transpose64<<<dim3(32, 32), 256, 0, stream>>>(Vb, VTb);

  attn4<<<dim3(32, 16, 2), 256, 0, stream>>>(Qb, Kb, VTb, maskbias, Op0, Op1, Ms, Ss);

  attn_combine<<<2048, 256, 0, stream>>>(Op0, Op1, Ms, Ss, qmaskf, hatt);

  gemm_splitk<<<dim3(8, 32, 2), 256, 0, stream>>>(hatt, wo_b, WP, 1024, 1024, 512);

  add_ln_multi<2, 1, 0, 0><<<4096, 256, 0, stream>>>(q, WP, WP + 4194304, nullptr, nullptr,
                                                     nullptr, g1, be1, h1b);

  // FFN1: 8-phase 256^2 template, grid 16x16 = 256 blocks = 1/CU
  gemm_8ph<<<dim3(16, 16), 512, 0, stream>>>(h1b, w1_b, b1, ff1, 4096, 1024);

  gemm_splitk<<<dim3(8, 32, 4), 256, 0, stream>>>(ff1, w2_b, Fp, 1024, 4096, 1024);

  add_ln_multi<4, 0, 1, 1><<<4096, 256, 0, stream>>>(h1b, Fp, Fp + 4194304, Fp + 2 * 4194304,
                                                     Fp + 3 * 4194304, b2, g2, be2, out);
}

// Round 14
// 279.384 us; speedup vs baseline: 1.2235x; 1.2235x over previous
//
#include <hip/hip_runtime.h>

typedef unsigned short u16;
typedef unsigned int u32;
typedef __attribute__((ext_vector_type(8))) __bf16 bf16x8;
typedef __attribute__((ext_vector_type(4))) float f32x4;
typedef __attribute__((ext_vector_type(16))) float f32x16;
typedef __attribute__((ext_vector_type(4))) unsigned short u16x4;
typedef __attribute__((ext_vector_type(8))) unsigned short u16x8;
typedef __attribute__((ext_vector_type(2))) int i32x2;

#define LOG2E 1.44269504088896340736f

__device__ __forceinline__ u16 f2bf(float f) {
  union { float f; unsigned u; } c; c.f = f;
  unsigned r = c.u + 0x7FFFu + ((c.u >> 16) & 1u);
  return (u16)(r >> 16);
}
__device__ __forceinline__ float bf2f(u16 h) {
  union { unsigned u; float f; } c; c.u = ((unsigned)h) << 16;
  return c.f;
}
__device__ __forceinline__ float max3f(float a, float b, float c) {
  return fmaxf(fmaxf(a, b), c);
}

__device__ __forceinline__ void gload_lds16(const u16* g, u16* l) {
  __builtin_amdgcn_global_load_lds((const __attribute__((address_space(1))) unsigned int*)g,
                                   (__attribute__((address_space(3))) unsigned int*)l, 16, 0, 0);
}

// XCD-chunked block remap (T1). Requires nwg % 8 == 0.
__device__ __forceinline__ void xcd_remap(int& bn, int& bm, int& bz) {
  int gx = gridDim.x, gxy = gridDim.x * gridDim.y;
  int lin = blockIdx.z * gxy + blockIdx.y * gx + blockIdx.x;
  int nwg = gxy * gridDim.z;
  int q = nwg >> 3;
  int w = (lin & 7) * q + (lin >> 3);
  bz = w / gxy;
  int rem = w - bz * gxy;
  bm = rem / gx;
  bn = rem - bm * gx;
}

// fast exact GELU: erf via Abramowitz-Stegun 7.1.26 (|eps| <= 1.5e-7)
__device__ __forceinline__ float gelu_fast(float x) {
  float z = fabsf(x) * 0.70710678118654752f;
  float t = 1.0f / (1.0f + 0.3275911f * z);
  float poly = t * (0.254829592f + t * (-0.284496736f + t * (1.421413741f +
               t * (-1.453152027f + t * 1.061405429f))));
  float e = __builtin_amdgcn_exp2f(-z * z * LOG2E);
  float erfz = 1.0f - poly * e;
  float s = (x >= 0.0f) ? erfz : -erfz;
  return 0.5f * x * (1.0f + s);
}

// ---------------- fused f32 -> bf16 conversion (all 9 tensors, one launch) ----------------
__global__ __launch_bounds__(256) void cvt_all(
    const float* __restrict__ s0, const float* __restrict__ s1, const float* __restrict__ s2,
    const float* __restrict__ s3, const float* __restrict__ s4, const float* __restrict__ s5,
    const float* __restrict__ s6, const float* __restrict__ s7, const float* __restrict__ s8,
    u16* __restrict__ d0, u16* __restrict__ d1, u16* __restrict__ d2,
    u16* __restrict__ d3, u16* __restrict__ d4, u16* __restrict__ d5,
    u16* __restrict__ d6, u16* __restrict__ d7, u16* __restrict__ d8) {
  int i = blockIdx.x * 256 + threadIdx.x;
  if (i >= 6291456) return;
  const float* src; u16* dst; int off;
  if (i < 3145728) {
    if (i < 1048576)      { src = s0; dst = d0; off = 0; }
    else if (i < 2097152) { src = s1; dst = d1; off = 1048576; }
    else                  { src = s2; dst = d2; off = 2097152; }
  } else if (i < 4194304) {
    if (i < 3407872)      { src = s3; dst = d3; off = 3145728; }
    else if (i < 3670016) { src = s4; dst = d4; off = 3407872; }
    else if (i < 3932160) { src = s5; dst = d5; off = 3670016; }
    else                  { src = s6; dst = d6; off = 3932160; }
  } else {
    if (i < 5242880)      { src = s7; dst = d7; off = 4194304; }
    else                  { src = s8; dst = d8; off = 5242880; }
  }
  int j = i - off;
  f32x4 v = ((const f32x4*)src)[j];
  u16x4 o;
  o[0] = f2bf(v[0]); o[1] = f2bf(v[1]); o[2] = f2bf(v[2]); o[3] = f2bf(v[3]);
  ((u16x4*)dst)[j] = o;
}

// ---------------- mask expansion (bool/int32 autodetect) ----------------
__global__ void build_masks(const void* __restrict__ pm, float* __restrict__ maskbias,
                            float* __restrict__ qmask, int n) {
  __shared__ int sflag;
  if (threadIdx.x == 0) sflag = 0;
  __syncthreads();
  const unsigned* pw = (const unsigned*)pm;
  int nwords = n / 4;
  int local = 0;
  for (int i = threadIdx.x; i < nwords; i += blockDim.x)
    if (pw[i] > 1u) local = 1;
  if (local) atomicOr(&sflag, 1);
  __syncthreads();
  bool isbool = (sflag != 0);
  for (int i = threadIdx.x; i < n; i += blockDim.x) {
    int m = isbool ? (int)((const unsigned char*)pm)[i] : ((const int*)pm)[i];
    maskbias[i] = m ? 0.0f : -2e30f;
    qmask[i]    = m ? 1.0f : 0.0f;
  }
}

// ---------------- GEMM core v6: 4 waves x (64x64), BK=32 2-buf issue-early, 3 blk/CU ------
// EPI: 0 none, 1 +bias, 2 +bias+GELU, 3 transposed V store (C = VT[bh][64][2048])
template<int EPI>
__device__ __forceinline__ void gemm_core(const u16* __restrict__ A, const u16* __restrict__ Bw,
                                          const float* __restrict__ bias, u16* __restrict__ C,
                                          int N, int Kstride, int Klen, int bn, int bm, int tid) {
  __shared__ u16 smem[2][8192];
  int wave = tid >> 6, lane = tid & 63;
  int l15 = lane & 15, l4 = lane >> 4;
  int wr = (wave >> 1) * 64, wc = (wave & 1) * 64;
  int mrow0 = bm * 128, ncol0 = bn * 128;
  int srow = lane >> 2;
  int scol = (lane & 3) * 8;

  const u16* asrc0 = A  + (size_t)(mrow0 + (wave * 2 + 0) * 16 + srow) * Kstride + scol;
  const u16* asrc1 = A  + (size_t)(mrow0 + (wave * 2 + 1) * 16 + srow) * Kstride + scol;
  const u16* bsrc0 = Bw + (size_t)(ncol0 + (wave * 2 + 0) * 16 + srow) * Kstride + scol;
  const u16* bsrc1 = Bw + (size_t)(ncol0 + (wave * 2 + 1) * 16 + srow) * Kstride + scol;
  u16* ad0 = &smem[0][(wave * 2 + 0) * 512];
  u16* ad1 = &smem[0][(wave * 2 + 1) * 512];
  u16* bd0 = &smem[0][4096 + (wave * 2 + 0) * 512];
  u16* bd1 = &smem[0][4096 + (wave * 2 + 1) * 512];

  auto stage = [&](int buf, int k0) {
    gload_lds16(asrc0 + k0, ad0 + buf * 8192);
    gload_lds16(asrc1 + k0, ad1 + buf * 8192);
    gload_lds16(bsrc0 + k0, bd0 + buf * 8192);
    gload_lds16(bsrc1 + k0, bd1 + buf * 8192);
  };

  f32x4 acc[4][4];
#pragma unroll
  for (int i = 0; i < 4; i++)
#pragma unroll
    for (int j = 0; j < 4; j++) acc[i][j] = (f32x4)0.0f;

  int nsteps = Klen >> 5;
  stage(0, 0);
  for (int s = 0; s < nsteps; s++) {
    asm volatile("s_waitcnt vmcnt(0)" ::: "memory");  // tile s landed (flew during step s-1)
    __builtin_amdgcn_s_barrier();
    if (s + 1 < nsteps) stage((s + 1) & 1, (s + 1) << 5);  // issue-early under this step
    const u16* as = &smem[s & 1][0];
    const u16* bs = &smem[s & 1][4096];
    bf16x8 af[4], bfr[4];
#pragma unroll
    for (int mi = 0; mi < 4; mi++) af[mi]  = *(const bf16x8*)(as + (wr + mi * 16 + l15) * 32 + l4 * 8);
#pragma unroll
    for (int ni = 0; ni < 4; ni++) bfr[ni] = *(const bf16x8*)(bs + (wc + ni * 16 + l15) * 32 + l4 * 8);
#pragma unroll
    for (int mi = 0; mi < 4; mi++)
#pragma unroll
      for (int ni = 0; ni < 4; ni++)
        acc[mi][ni] = __builtin_amdgcn_mfma_f32_16x16x32_bf16(af[mi], bfr[ni], acc[mi][ni], 0, 0, 0);
  }

  __syncthreads();
  u16* ct = &smem[0][0];
  if constexpr (EPI == 3) {
    // transposed V store: ct stride 137 (2-way-free banks both sides), store along tokens
#pragma unroll
    for (int p = 0; p < 2; p++) {
      if (p) __syncthreads();
      if ((wave >> 1) == p) {
#pragma unroll
        for (int ni = 0; ni < 4; ni++)
#pragma unroll
          for (int mi = 0; mi < 4; mi++)
#pragma unroll
            for (int r = 0; r < 4; r++)
              ct[(mi * 16 + l4 * 4 + r) * 137 + wc + ni * 16 + l15] = f2bf(acc[mi][ni][r]);
      }
      __syncthreads();
      int tr0 = mrow0 + p * 64;                 // 64-token chunk (within one batch)
      int b = tr0 >> 11, tinb = tr0 & 2047;
#pragma unroll
      for (int it = 0; it < 4; it++) {
        int idx = it * 256 + tid;               // 0..1023
        int tch = idx & 7, d = idx >> 3;        // d 0..127
        int t0 = tch * 8;
        u16x8 o;
#pragma unroll
        for (int e = 0; e < 8; e++) o[e] = ct[(t0 + e) * 137 + d];
        int head = (ncol0 + d) >> 6, dd = (ncol0 + d) & 63;
        size_t off = (size_t)(b * 16 + head) * 131072 + (size_t)dd * 2048 + tinb + t0;
        *(u16x8*)(C + off) = o;
      }
    }
  } else {
#pragma unroll
    for (int p = 0; p < 2; p++) {
      if (p) __syncthreads();
      if ((wave >> 1) == p) {
#pragma unroll
        for (int ni = 0; ni < 4; ni++) {
          int gcol = ncol0 + wc + ni * 16 + l15;
          float bv = (EPI > 0) ? bias[gcol] : 0.0f;
#pragma unroll
          for (int mi = 0; mi < 4; mi++) {
#pragma unroll
            for (int r = 0; r < 4; r++) {
              float v = acc[mi][ni][r] + bv;
              if (EPI == 2) v = gelu_fast(v);
              ct[(mi * 16 + l4 * 4 + r) * 136 + wc + ni * 16 + l15] = f2bf(v);
            }
          }
        }
      }
      __syncthreads();
      int lrow = tid >> 2, cq = tid & 3;
#pragma unroll
      for (int j = 0; j < 4; j++) {
        int col = cq * 8 + j * 32;
        u16x8 vv = *(const u16x8*)(ct + lrow * 136 + col);
        *(u16x8*)(C + (size_t)(mrow0 + p * 64 + lrow) * N + ncol0 + col) = vv;
      }
    }
  }
}

template<int EPI>
__global__ __launch_bounds__(256, 3) void gemm_bt(const u16* __restrict__ A, const u16* __restrict__ Bw,
                                                  const float* __restrict__ bias, u16* __restrict__ C,
                                                  int N, int K) {
  int bn, bm, bz;
  xcd_remap(bn, bm, bz);
  gemm_core<EPI>(A, Bw, bias, C, N, K, K, bn, bm, threadIdx.x);
}

__global__ __launch_bounds__(256, 3) void gemm_splitk(const u16* __restrict__ A, const u16* __restrict__ Bw,
                                                      u16* __restrict__ P, int N, int Kstride, int Kc) {
  int bn, bm, bz;
  xcd_remap(bn, bm, bz);
  size_t M = (size_t)gridDim.y * 128;
  gemm_core<0>(A + (size_t)bz * Kc, Bw + (size_t)bz * Kc, nullptr,
               P + (size_t)bz * M * N, N, Kstride, Kc, bn, bm, threadIdx.x);
}

// Q and K projections (z in {0,1})
__global__ __launch_bounds__(256, 3) void gemm_qkv2(const u16* __restrict__ qb, const u16* __restrict__ kb,
                                                    const u16* __restrict__ wq, const u16* __restrict__ wk,
                                                    u16* __restrict__ Qo, u16* __restrict__ Ko) {
  int bn, bm, bz;
  xcd_remap(bn, bm, bz);
  const u16* A; const u16* W; u16* C;
  if (bz == 0) { A = qb; W = wq; C = Qo; }
  else         { A = kb; W = wk; C = Ko; }
  gemm_core<0>(A, W, nullptr, C, 1024, 1024, 1024, bn, bm, threadIdx.x);
}

// V projection with transposed store -> VT[bh][64][2048]
__global__ __launch_bounds__(256, 3) void gemm_v(const u16* __restrict__ vb, const u16* __restrict__ wv,
                                                 u16* __restrict__ VT) {
  int bn, bm, bz;
  xcd_remap(bn, bm, bz);
  gemm_core<3>(vb, wv, nullptr, VT, 1024, 1024, 1024, bn, bm, threadIdx.x);
}

// ---------------- flash attention v5 + T5 setprio: LDS K/V, swapped-QK, permlane softmax --
__global__ __launch_bounds__(256, 4) void attn4(const u16* __restrict__ Q, const u16* __restrict__ Kg,
                                                const u16* __restrict__ VT,
                                                const float* __restrict__ maskbias,
                                                u16* __restrict__ O0, u16* __restrict__ O1,
                                                float* __restrict__ Ms, float* __restrict__ Ss) {
  const int T = 2048;
  int bh = blockIdx.x;
  int qt = blockIdx.y;
  int sp = blockIdx.z;
  int b = bh >> 4;
  const u16* Qh = Q  + (size_t)bh * T * 64;
  const u16* Kh = Kg + (size_t)bh * T * 64;
  const u16* Vh = VT + (size_t)bh * T * 64;
  u16* Oh = (sp ? O1 : O0) + (size_t)bh * T * 64;
  const float* mb = maskbias + b * T + sp * 1024;
  int tid = threadIdx.x, w = tid >> 6, l = tid & 63;
  int q32 = l & 31, h = l >> 5;
  int qbase = qt * 128 + w * 32;
  const float C = 0.125f * LOG2E;

  __shared__ u16 Ks[2][4096];
  __shared__ u16 Vs[2][4096];

  bf16x8 qf[4];
#pragma unroll
  for (int dc = 0; dc < 4; dc++)
    qf[dc] = *(const bf16x8*)(Qh + (size_t)(qbase + q32) * 64 + dc * 16 + h * 8);

  int rl = l >> 3, ob = (l & 7) * 16;
  int osw = ob ^ (rl << 4);
  int r0 = w * 16 + rl, r1 = w * 16 + 8 + rl;
  const u16* pK0 = Kh + (size_t)(sp * 1024 + r0) * 64 + (osw >> 1);
  const u16* pK1 = Kh + (size_t)(sp * 1024 + r1) * 64 + (osw >> 1);
  const u16* pV0 = Vh + (size_t)r0 * 2048 + sp * 1024 + (osw >> 1);
  const u16* pV1 = Vh + (size_t)r1 * 2048 + sp * 1024 + (osw >> 1);
  u16* dK0 = &Ks[0][0] + (w * 16) * 64;
  u16* dK1 = &Ks[0][0] + (w * 16 + 8) * 64;
  u16* dV0 = &Vs[0][0] + (w * 16) * 64;
  u16* dV1 = &Vs[0][0] + (w * 16 + 8) * 64;

  auto stage = [&](int buf) {
    gload_lds16(pK0, dK0 + buf * 4096);
    gload_lds16(pK1, dK1 + buf * 4096);
    gload_lds16(pV0, dV0 + buf * 4096);
    gload_lds16(pV1, dV1 + buf * 4096);
    pK0 += 4096; pK1 += 4096; pV0 += 64; pV1 += 64;
  };

  f32x16 acc[2];
  acc[0] = (f32x16)0.0f; acc[1] = (f32x16)0.0f;
  float m_ = -3e30f, s_ = 0.0f;

  int swz = (q32 & 7) << 4;

  stage(0);
  for (int t = 0; t < 16; t++) {
    int cur = t & 1;
    __syncthreads();
    if (t < 15) stage(cur ^ 1);
    const char* ksb = (const char*)(&Ks[0][0] + cur * 4096);
    const char* vsb = (const char*)(&Vs[0][0] + cur * 4096);

    bf16x8 kf[2][4];
#pragma unroll
    for (int kvc = 0; kvc < 2; kvc++)
#pragma unroll
      for (int dc = 0; dc < 4; dc++)
        kf[kvc][dc] = *(const bf16x8*)(ksb + (kvc * 32 + q32) * 128 + ((dc * 32 + h * 16) ^ swz));

    f32x16 st[2];
    st[0] = (f32x16)0.0f; st[1] = (f32x16)0.0f;
    __builtin_amdgcn_s_setprio(1);
#pragma unroll
    for (int kvc = 0; kvc < 2; kvc++)
#pragma unroll
      for (int dc = 0; dc < 4; dc++)
        st[kvc] = __builtin_amdgcn_mfma_f32_32x32x16_bf16(kf[kvc][dc], qf[dc], st[kvc], 0, 0, 0);
    __builtin_amdgcn_s_setprio(0);

    float p[32];
#pragma unroll
    for (int kvc = 0; kvc < 2; kvc++) {
#pragma unroll
      for (int g = 0; g < 4; g++) {
        f32x4 mv = *(const f32x4*)(mb + t * 64 + kvc * 32 + g * 8 + h * 4);
#pragma unroll
        for (int r = 0; r < 4; r++)
          p[kvc * 16 + g * 4 + r] = st[kvc][g * 4 + r] * C + mv[r];
      }
    }
    float ma = p[0], mb2 = p[16];
#pragma unroll
    for (int i = 0; i < 7; i++) {
      ma  = max3f(ma,  p[1 + 2 * i],  p[2 + 2 * i]);
      mb2 = max3f(mb2, p[17 + 2 * i], p[18 + 2 * i]);
    }
    ma = fmaxf(ma, p[15]); mb2 = fmaxf(mb2, p[31]);
    float pmax = fmaxf(ma, mb2);
    i32x2 pr = __builtin_amdgcn_permlane32_swap(__float_as_int(pmax), __float_as_int(pmax), false, false);
    pmax = fmaxf(__int_as_float(pr[0]), __int_as_float(pr[1]));

    if (__any(pmax - m_ > 8.0f)) {
      float mnew = fmaxf(m_, pmax);
      float fsc = __builtin_amdgcn_exp2f(m_ - mnew);
      s_ *= fsc;
      m_ = mnew;
#pragma unroll
      for (int g = 0; g < 4; g++)
#pragma unroll
        for (int r = 0; r < 4; r++) {
          float f = __shfl(fsc, g * 8 + h * 4 + r);
          acc[0][g * 4 + r] *= f;
          acc[1][g * 4 + r] *= f;
        }
    }

    float rsum = 0.0f;
    u32 wds[16];
#pragma unroll
    for (int i = 0; i < 16; i++) {
      float a = __builtin_amdgcn_exp2f(p[2 * i] - m_);
      float bq = __builtin_amdgcn_exp2f(p[2 * i + 1] - m_);
      rsum += a + bq;
      union { __bf16 h2[2]; u32 u; } cv;
      cv.h2[0] = (__bf16)a; cv.h2[1] = (__bf16)bq;
      wds[i] = cv.u;
    }
    i32x2 sr = __builtin_amdgcn_permlane32_swap(__float_as_int(rsum), __float_as_int(rsum), false, false);
    rsum = __int_as_float(sr[0]) + __int_as_float(sr[1]);
    s_ += rsum;

#pragma unroll
    for (int kvc = 0; kvc < 2; kvc++) {
      int bse = kvc * 8;
      i32x2 r02 = __builtin_amdgcn_permlane32_swap((int)wds[bse + 0], (int)wds[bse + 2], false, false);
      i32x2 r13 = __builtin_amdgcn_permlane32_swap((int)wds[bse + 1], (int)wds[bse + 3], false, false);
      i32x2 r46 = __builtin_amdgcn_permlane32_swap((int)wds[bse + 4], (int)wds[bse + 6], false, false);
      i32x2 r57 = __builtin_amdgcn_permlane32_swap((int)wds[bse + 5], (int)wds[bse + 7], false, false);
      union { u32 u[4]; bf16x8 v; } pa0, pa1;
      pa0.u[0] = (u32)r02[0]; pa0.u[1] = (u32)r13[0]; pa0.u[2] = (u32)r02[1]; pa0.u[3] = (u32)r13[1];
      pa1.u[0] = (u32)r46[0]; pa1.u[1] = (u32)r57[0]; pa1.u[2] = (u32)r46[1]; pa1.u[3] = (u32)r57[1];
      __builtin_amdgcn_s_setprio(1);
#pragma unroll
      for (int cl = 0; cl < 2; cl++) {
        bf16x8 pa = cl ? pa1.v : pa0.v;
        int cg = kvc * 2 + cl;
#pragma unroll
        for (int dblk = 0; dblk < 2; dblk++) {
          bf16x8 vf = *(const bf16x8*)(vsb + (dblk * 32 + q32) * 128 + ((cg * 32 + h * 16) ^ swz));
          acc[dblk] = __builtin_amdgcn_mfma_f32_32x32x16_bf16(pa, vf, acc[dblk], 0, 0, 0);
        }
      }
      __builtin_amdgcn_s_setprio(0);
    }
  }

#pragma unroll
  for (int g = 0; g < 4; g++) {
#pragma unroll
    for (int r = 0; r < 4; r++) {
      int row = g * 8 + h * 4 + r;
#pragma unroll
      for (int dblk = 0; dblk < 2; dblk++)
        Oh[(size_t)(qbase + row) * 64 + dblk * 32 + q32] = f2bf(acc[dblk][g * 4 + r]);
    }
  }
  if (h == 0) {
    int ro = sp * 65536 + bh * 2048 + qbase + q32;
    Ms[ro] = m_;
    Ss[ro] = s_;
  }
}

// ---------------- split-KV combine (2 splits) ----------------
__global__ __launch_bounds__(256) void attn_combine(const u16* __restrict__ O0, const u16* __restrict__ O1,
                                                    const float* __restrict__ Ms, const float* __restrict__ Ss,
                                                    const float* __restrict__ qmaskf, u16* __restrict__ out) {
  int idx = blockIdx.x * 256 + threadIdx.x;
  int row = idx >> 3;
  int d8 = (idx & 7) * 8;
  int bh = row >> 11, r = row & 2047, b = bh >> 4;
  float m0 = Ms[row], m1 = Ms[65536 + row];
  float mstar = fmaxf(m0, m1);
  float w0 = __builtin_amdgcn_exp2f(m0 - mstar);
  float w1 = __builtin_amdgcn_exp2f(m1 - mstar);
  float den = w0 * Ss[row] + w1 * Ss[65536 + row];
  float scale = qmaskf[b * 2048 + r] / den;
  size_t base = (size_t)row * 64 + d8;
  u16x8 a0 = *(const u16x8*)(O0 + base);
  u16x8 a1 = *(const u16x8*)(O1 + base);
  u16x8 o;
#pragma unroll
  for (int e = 0; e < 8; e++)
    o[e] = f2bf((w0 * bf2f(a0[e]) + w1 * bf2f(a1[e])) * scale);
  *(u16x8*)(out + base) = o;
}

// ---------------- residual + split-K partial sum + (bias) + layernorm ----------------
template<int NP, int A_F32, int ADD_BIAS, int OUT_F32>
__global__ __launch_bounds__(256) void add_ln_multi(const void* __restrict__ Ap,
                                                    const u16* __restrict__ P0, const u16* __restrict__ P1,
                                                    const u16* __restrict__ P2, const u16* __restrict__ P3,
                                                    const float* __restrict__ bias,
                                                    const float* __restrict__ g, const float* __restrict__ be,
                                                    void* __restrict__ outp) {
  int row = blockIdx.x, tid = threadIdx.x;
  int lane = tid & 63, wave = tid >> 6;
  size_t rb = (size_t)row * 1024;
  float x[4];
  if (A_F32) {
    f32x4 a = ((const f32x4*)((const float*)Ap + rb))[tid];
#pragma unroll
    for (int j = 0; j < 4; j++) x[j] = a[j];
  } else {
    u16x4 au = ((const u16x4*)((const u16*)Ap + rb))[tid];
#pragma unroll
    for (int j = 0; j < 4; j++) x[j] = bf2f(au[j]);
  }
  {
    u16x4 p = ((const u16x4*)(P0 + rb))[tid];
#pragma unroll
    for (int j = 0; j < 4; j++) x[j] += bf2f(p[j]);
  }
  if (NP > 1) {
    u16x4 p = ((const u16x4*)(P1 + rb))[tid];
#pragma unroll
    for (int j = 0; j < 4; j++) x[j] += bf2f(p[j]);
  }
  if (NP > 2) {
    u16x4 p = ((const u16x4*)(P2 + rb))[tid];
#pragma unroll
    for (int j = 0; j < 4; j++) x[j] += bf2f(p[j]);
  }
  if (NP > 3) {
    u16x4 p = ((const u16x4*)(P3 + rb))[tid];
#pragma unroll
    for (int j = 0; j < 4; j++) x[j] += bf2f(p[j]);
  }
  if (ADD_BIAS) {
    f32x4 bv = ((const f32x4*)bias)[tid];
#pragma unroll
    for (int j = 0; j < 4; j++) x[j] += bv[j];
  }
  float s = x[0] + x[1] + x[2] + x[3];
  float q = x[0] * x[0] + x[1] * x[1] + x[2] * x[2] + x[3] * x[3];
#pragma unroll
  for (int m = 1; m < 64; m <<= 1) { s += __shfl_xor(s, m); q += __shfl_xor(q, m); }
  __shared__ float rs[4], rq[4];
  if (lane == 0) { rs[wave] = s; rq[wave] = q; }
  __syncthreads();
  float S = rs[0] + rs[1] + rs[2] + rs[3];
  float Qq = rq[0] + rq[1] + rq[2] + rq[3];
  float mean = S * (1.0f / 1024.0f);
  float var = Qq * (1.0f / 1024.0f) - mean * mean;
  float rstd = rsqrtf(var + 1e-5f);
  if (OUT_F32) {
    f32x4 y;
#pragma unroll
    for (int j = 0; j < 4; j++) { int col = tid * 4 + j; y[j] = (x[j] - mean) * rstd * g[col] + be[col]; }
    ((f32x4*)((float*)outp + rb))[tid] = y;
  } else {
    u16x4 y;
#pragma unroll
    for (int j = 0; j < 4; j++) { int col = tid * 4 + j; y[j] = f2bf((x[j] - mean) * rstd * g[col] + be[col]); }
    ((u16x4*)((u16*)outp + rb))[tid] = y;
  }
}

// ---------------- launch ----------------
extern "C" void kernel_launch(void* const* d_in, const int* in_sizes, int n_in,
                              void* d_out, int out_size, void* d_ws, size_t ws_size,
                              hipStream_t stream) {
  const float* q   = (const float*)d_in[0];
  const float* k   = (const float*)d_in[1];
  const float* v   = (const float*)d_in[2];
  const void*  pad = d_in[3];
  const float* Wq  = (const float*)d_in[4];
  const float* Wk  = (const float*)d_in[5];
  const float* Wv  = (const float*)d_in[6];
  const float* Wo  = (const float*)d_in[7];
  const float* W1  = (const float*)d_in[8];
  const float* b1  = (const float*)d_in[9];
  const float* W2  = (const float*)d_in[10];
  const float* b2  = (const float*)d_in[11];
  const float* g1  = (const float*)d_in[12];
  const float* be1 = (const float*)d_in[13];
  const float* g2  = (const float*)d_in[14];
  const float* be2 = (const float*)d_in[15];
  float* out = (float*)d_out;
  char* ws = (char*)d_ws;
  const size_t MB = 1u << 20;

  u16* wq_b = (u16*)(ws + 0 * MB);
  u16* wk_b = (u16*)(ws + 2 * MB);
  u16* wv_b = (u16*)(ws + 4 * MB);
  u16* wo_b = (u16*)(ws + 6 * MB);
  u16* w1_b = (u16*)(ws + 8 * MB);
  u16* w2_b = (u16*)(ws + 16 * MB);
  u16* qb   = (u16*)(ws + 24 * MB);
  u16* kb   = (u16*)(ws + 32 * MB);
  u16* vb   = (u16*)(ws + 40 * MB);
  u16* Qb   = (u16*)(ws + 48 * MB);
  u16* Kb   = (u16*)(ws + 56 * MB);
  u16* VTb  = (u16*)(ws + 72 * MB);
  u16* hatt = (u16*)(ws + 80 * MB);
  u16* Op0  = (u16*)(ws + 24 * MB);   // qb dead after QKV
  u16* Op1  = (u16*)(ws + 32 * MB);   // kb dead
  float* Ms = (float*)(ws + 88 * MB);
  float* Ss = (float*)(ws + 89 * MB);
  u16* WP   = (u16*)(ws + 40 * MB);   // Wo split-K partials x2 (vb dead): 40-56
  u16* h1b  = (u16*)(ws + 24 * MB);   // Op0 dead after combine
  u16* ff1  = (u16*)(ws + 32 * MB);   // Op1/WP dead after LN1: 32-64 (32 MB)
  u16* Fp   = (u16*)(ws + 64 * MB);   // FFN2 split-K partials x4: 64-96
  float* maskbias = (float*)(ws + 96 * MB);
  float* qmaskf   = (float*)(ws + 96 * MB + 16384);

  build_masks<<<1, 256, 0, stream>>>(pad, maskbias, qmaskf, in_sizes[3]);

  cvt_all<<<24576, 256, 0, stream>>>(q, k, v, Wq, Wk, Wv, Wo, W1, W2,
                                     qb, kb, vb, wq_b, wk_b, wv_b, wo_b, w1_b, w2_b);

  // Q,K projections + V projection with fused transpose (replaces transpose64)
  gemm_qkv2<<<dim3(8, 32, 2), 256, 0, stream>>>(qb, kb, wq_b, wk_b, Qb, Kb);
  gemm_v<<<dim3(8, 32), 256, 0, stream>>>(vb, wv_b, VTb);

  attn4<<<dim3(32, 16, 2), 256, 0, stream>>>(Qb, Kb, VTb, maskbias, Op0, Op1, Ms, Ss);

  attn_combine<<<2048, 256, 0, stream>>>(Op0, Op1, Ms, Ss, qmaskf, hatt);

  // Wo: split-K x2 (Kc=512)
  gemm_splitk<<<dim3(8, 32, 2), 256, 0, stream>>>(hatt, wo_b, WP, 1024, 1024, 512);

  // LN1: q + WP0 + WP1 -> h1b (bf16)
  add_ln_multi<2, 1, 0, 0><<<4096, 256, 0, stream>>>(q, WP, WP + 4194304, nullptr, nullptr,
                                                     nullptr, g1, be1, h1b);

  // FFN1: h1 @ W1^T + b1, GELU -> ff1 (proven v6 structure)
  gemm_bt<2><<<dim3(32, 32), 256, 0, stream>>>(h1b, w1_b, b1, ff1, 4096, 1024);

  // FFN2: split-K x4 (Kc=1024)
  gemm_splitk<<<dim3(8, 32, 4), 256, 0, stream>>>(ff1, w2_b, Fp, 1024, 4096, 1024);

  // LN2: h1 + sum(Fp) + b2 -> out (f32)
  add_ln_multi<4, 0, 1, 1><<<4096, 256, 0, stream>>>(h1b, Fp, Fp + 4194304, Fp + 2 * 4194304,
                                                     Fp + 3 * 4194304, b2, g2, be2, out);
}

// Round 15
// 272.834 us; speedup vs baseline: 1.2529x; 1.0240x over previous
//
#include <hip/hip_runtime.h>

typedef unsigned short u16;
typedef unsigned int u32;
typedef __attribute__((ext_vector_type(8))) __bf16 bf16x8;
typedef __attribute__((ext_vector_type(4))) float f32x4;
typedef __attribute__((ext_vector_type(16))) float f32x16;
typedef __attribute__((ext_vector_type(4))) unsigned short u16x4;
typedef __attribute__((ext_vector_type(8))) unsigned short u16x8;
typedef __attribute__((ext_vector_type(2))) int i32x2;

#define LOG2E 1.44269504088896340736f

__device__ __forceinline__ u16 f2bf(float f) {
  union { float f; unsigned u; } c; c.f = f;
  unsigned r = c.u + 0x7FFFu + ((c.u >> 16) & 1u);
  return (u16)(r >> 16);
}
__device__ __forceinline__ float bf2f(u16 h) {
  union { unsigned u; float f; } c; c.u = ((unsigned)h) << 16;
  return c.f;
}
__device__ __forceinline__ float max3f(float a, float b, float c) {
  return fmaxf(fmaxf(a, b), c);
}

__device__ __forceinline__ void gload_lds16(const u16* g, u16* l) {
  __builtin_amdgcn_global_load_lds((const __attribute__((address_space(1))) unsigned int*)g,
                                   (__attribute__((address_space(3))) unsigned int*)l, 16, 0, 0);
}

// fast exact GELU: erf via Abramowitz-Stegun 7.1.26 (|eps| <= 1.5e-7)
__device__ __forceinline__ float gelu_fast(float x) {
  float z = fabsf(x) * 0.70710678118654752f;
  float t = 1.0f / (1.0f + 0.3275911f * z);
  float poly = t * (0.254829592f + t * (-0.284496736f + t * (1.421413741f +
               t * (-1.453152027f + t * 1.061405429f))));
  float e = __builtin_amdgcn_exp2f(-z * z * LOG2E);
  float erfz = 1.0f - poly * e;
  float s = (x >= 0.0f) ? erfz : -erfz;
  return 0.5f * x * (1.0f + s);
}

// ---------------- fused f32 -> bf16 conversion (all 9 tensors, one launch) ----------------
__global__ __launch_bounds__(256) void cvt_all(
    const float* __restrict__ s0, const float* __restrict__ s1, const float* __restrict__ s2,
    const float* __restrict__ s3, const float* __restrict__ s4, const float* __restrict__ s5,
    const float* __restrict__ s6, const float* __restrict__ s7, const float* __restrict__ s8,
    u16* __restrict__ d0, u16* __restrict__ d1, u16* __restrict__ d2,
    u16* __restrict__ d3, u16* __restrict__ d4, u16* __restrict__ d5,
    u16* __restrict__ d6, u16* __restrict__ d7, u16* __restrict__ d8) {
  int i = blockIdx.x * 256 + threadIdx.x;
  if (i >= 6291456) return;
  const float* src; u16* dst; int off;
  if (i < 3145728) {
    if (i < 1048576)      { src = s0; dst = d0; off = 0; }
    else if (i < 2097152) { src = s1; dst = d1; off = 1048576; }
    else                  { src = s2; dst = d2; off = 2097152; }
  } else if (i < 4194304) {
    if (i < 3407872)      { src = s3; dst = d3; off = 3145728; }
    else if (i < 3670016) { src = s4; dst = d4; off = 3407872; }
    else if (i < 3932160) { src = s5; dst = d5; off = 3670016; }
    else                  { src = s6; dst = d6; off = 3932160; }
  } else {
    if (i < 5242880)      { src = s7; dst = d7; off = 4194304; }
    else                  { src = s8; dst = d8; off = 5242880; }
  }
  int j = i - off;
  f32x4 v = ((const f32x4*)src)[j];
  u16x4 o;
  o[0] = f2bf(v[0]); o[1] = f2bf(v[1]); o[2] = f2bf(v[2]); o[3] = f2bf(v[3]);
  ((u16x4*)dst)[j] = o;
}

// ---------------- mask expansion (bool/int32 autodetect) ----------------
__global__ void build_masks(const void* __restrict__ pm, float* __restrict__ maskbias,
                            float* __restrict__ qmask, int n) {
  __shared__ int sflag;
  if (threadIdx.x == 0) sflag = 0;
  __syncthreads();
  const unsigned* pw = (const unsigned*)pm;
  int nwords = n / 4;
  int local = 0;
  for (int i = threadIdx.x; i < nwords; i += blockDim.x)
    if (pw[i] > 1u) local = 1;
  if (local) atomicOr(&sflag, 1);
  __syncthreads();
  bool isbool = (sflag != 0);
  for (int i = threadIdx.x; i < n; i += blockDim.x) {
    int m = isbool ? (int)((const unsigned char*)pm)[i] : ((const int*)pm)[i];
    maskbias[i] = m ? 0.0f : -2e30f;
    qmask[i]    = m ? 1.0f : 0.0f;
  }
}

// ---------------- GEMM core v5: BK=64, swizzled LDS (2-way-free), 1 barrier/phase ----------
// C[M,N] = act(A[M,Klen] @ W[N,Klen]^T + bias) -> bf16.  512 threads/block, 64KB LDS.
template<int EPI>
__device__ __forceinline__ void gemm_core(const u16* __restrict__ A, const u16* __restrict__ Bw,
                                          const float* __restrict__ bias, u16* __restrict__ C,
                                          int N, int Kstride, int Klen, int bn, int bm, int tid) {
  __shared__ u16 smem[2][16384];   // [buf][ A 0..8191 | B 8192..16383 ]  64 KB
  int wave = tid >> 6, lane = tid & 63;
  int l15 = lane & 15, l4 = lane >> 4;
  int wr = (wave >> 1) * 32;       // 4 wave-rows over 128
  int wc = (wave & 1) * 64;        // 2 wave-cols over 128
  int mrow0 = bm * 128, ncol0 = bn * 128;
  int rl = lane >> 3;                         // sub-row 0..7
  int osw = ((lane & 7) * 16) ^ (rl << 4);    // swizzled byte offset in 128B row
  int oswe = osw >> 1;                        // elements

  const u16* asrc0 = A  + (size_t)(mrow0 + wave * 16 + rl) * Kstride + oswe;
  const u16* asrc1 = A  + (size_t)(mrow0 + wave * 16 + 8 + rl) * Kstride + oswe;
  const u16* bsrc0 = Bw + (size_t)(ncol0 + wave * 16 + rl) * Kstride + oswe;
  const u16* bsrc1 = Bw + (size_t)(ncol0 + wave * 16 + 8 + rl) * Kstride + oswe;
  u16* adst0 = &smem[0][wave * 1024];
  u16* adst1 = &smem[0][wave * 1024 + 512];
  u16* bdst0 = &smem[0][8192 + wave * 1024];
  u16* bdst1 = &smem[0][8192 + wave * 1024 + 512];

  auto stage = [&](int buf, int k0) {
    gload_lds16(asrc0 + k0, adst0 + buf * 16384);
    gload_lds16(asrc1 + k0, adst1 + buf * 16384);
    gload_lds16(bsrc0 + k0, bdst0 + buf * 16384);
    gload_lds16(bsrc1 + k0, bdst1 + buf * 16384);
  };

  f32x4 acc[2][4];
#pragma unroll
  for (int i = 0; i < 2; i++)
#pragma unroll
    for (int j = 0; j < 4; j++) acc[i][j] = (f32x4)0.0f;

  int nsteps = Klen >> 6;
  stage(0, 0);
  int swzr = (l15 & 7) << 4;
  for (int s = 0; s < nsteps; s++) {
    asm volatile("s_waitcnt vmcnt(0)" ::: "memory");  // tile s landed (flew during phase s-1)
    __builtin_amdgcn_s_barrier();
    if (s + 1 < nsteps) stage((s + 1) & 1, (s + 1) << 6);  // issue-early, lands during this phase
    const char* as = (const char*)&smem[s & 1][0];
    const char* bs = (const char*)&smem[s & 1][8192];
#pragma unroll
    for (int kk = 0; kk < 2; kk++) {
      bf16x8 af[2], bfr[4];
#pragma unroll
      for (int mi = 0; mi < 2; mi++)
        af[mi]  = *(const bf16x8*)(as + (wr + mi * 16 + l15) * 128 + ((kk * 64 + l4 * 16) ^ swzr));
#pragma unroll
      for (int ni = 0; ni < 4; ni++)
        bfr[ni] = *(const bf16x8*)(bs + (wc + ni * 16 + l15) * 128 + ((kk * 64 + l4 * 16) ^ swzr));
#pragma unroll
      for (int mi = 0; mi < 2; mi++)
#pragma unroll
        for (int ni = 0; ni < 4; ni++)
          acc[mi][ni] = __builtin_amdgcn_mfma_f32_16x16x32_bf16(af[mi], bfr[ni], acc[mi][ni], 0, 0, 0);
    }
  }

  // epilogue: single-pass LDS bounce ([128][136] u16 = 34 KB) -> coalesced u16x8 stores
  __syncthreads();
  u16* ct = &smem[0][0];
#pragma unroll
  for (int ni = 0; ni < 4; ni++) {
    int gcol = ncol0 + wc + ni * 16 + l15;
    float bv = (EPI > 0) ? bias[gcol] : 0.0f;
#pragma unroll
    for (int mi = 0; mi < 2; mi++) {
#pragma unroll
      for (int r = 0; r < 4; r++) {
        float v = acc[mi][ni][r] + bv;
        if (EPI == 2) v = gelu_fast(v);
        ct[(wr + mi * 16 + l4 * 4 + r) * 136 + wc + ni * 16 + l15] = f2bf(v);
      }
    }
  }
  __syncthreads();
  int lrow = tid >> 2, cq = tid & 3;
#pragma unroll
  for (int j = 0; j < 4; j++) {
    int col = cq * 8 + j * 32;
    u16x8 vv = *(const u16x8*)(ct + lrow * 136 + col);
    *(u16x8*)(C + (size_t)(mrow0 + lrow) * N + ncol0 + col) = vv;
  }
}

template<int EPI>
__global__ __launch_bounds__(512, 4) void gemm_bt(const u16* __restrict__ A, const u16* __restrict__ Bw,
                                                  const float* __restrict__ bias, u16* __restrict__ C,
                                                  int N, int K) {
  gemm_core<EPI>(A, Bw, bias, C, N, K, K, blockIdx.x, blockIdx.y, threadIdx.x);
}

// split-K GEMM: blockIdx.z selects K-chunk of length Kc; writes bf16 partial at P + z*M*N
__global__ __launch_bounds__(512, 4) void gemm_splitk(const u16* __restrict__ A, const u16* __restrict__ Bw,
                                                      u16* __restrict__ P, int N, int Kstride, int Kc) {
  int z = blockIdx.z;
  size_t M = (size_t)gridDim.y * 128;
  gemm_core<0>(A + (size_t)z * Kc, Bw + (size_t)z * Kc, nullptr,
               P + (size_t)z * M * N, N, Kstride, Kc, blockIdx.x, blockIdx.y, threadIdx.x);
}

__global__ __launch_bounds__(512, 4) void gemm_qkv(const u16* __restrict__ qb, const u16* __restrict__ kb,
                                                   const u16* __restrict__ vb,
                                                   const u16* __restrict__ wq, const u16* __restrict__ wk,
                                                   const u16* __restrict__ wv,
                                                   u16* __restrict__ Qo, u16* __restrict__ Ko, u16* __restrict__ Vo) {
  const u16* A; const u16* W; u16* C;
  if (blockIdx.z == 0)      { A = qb; W = wq; C = Qo; }
  else if (blockIdx.z == 1) { A = kb; W = wk; C = Ko; }
  else                      { A = vb; W = wv; C = Vo; }
  gemm_core<0>(A, W, nullptr, C, 1024, 1024, 1024, blockIdx.x, blockIdx.y, threadIdx.x);
}

// ---------------- V transpose: [32][2048][64] -> [32][64][2048] ----------------
// (contiguous head reinterpretation per torch .view semantics — do NOT fuse into GEMM;
//  the correct head split makes a fused transposed store stride-16 scattered)
__global__ __launch_bounds__(256) void transpose64(const u16* __restrict__ in, u16* __restrict__ out) {
  int bh = blockIdx.y, tb = blockIdx.x;
  __shared__ u16 tile[64 * 72];
  int tid = threadIdx.x;
#pragma unroll
  for (int it = 0; it < 2; it++) {
    int idx = it * 256 + tid;
    int r = idx >> 3, c8 = (idx & 7) * 8;
    u16x8 v = *(const u16x8*)(in + ((size_t)bh * 2048 + tb * 64 + r) * 64 + c8);
    int byte = ((r * 72 + c8) * 2) ^ (((r >> 3) & 7) << 4);
    *(u16x8*)((char*)tile + byte) = v;
  }
  __syncthreads();
#pragma unroll
  for (int it = 0; it < 2; it++) {
    int idx = it * 256 + tid;
    int d = idx >> 3, t8 = (idx & 7) * 8;
    u16x8 o;
#pragma unroll
    for (int e = 0; e < 8; e++) {
      int t = t8 + e;
      int byte = ((t * 72 + d) * 2) ^ (((t >> 3) & 7) << 4);
      o[e] = *(const u16*)((const char*)tile + byte);
    }
    *(u16x8*)(out + ((size_t)bh * 64 + d) * 2048 + tb * 64 + t8) = o;
  }
}

// ---------------- flash attention v5 + T5 setprio: LDS K/V, swapped-QK, permlane softmax --
__global__ __launch_bounds__(256, 4) void attn4(const u16* __restrict__ Q, const u16* __restrict__ Kg,
                                                const u16* __restrict__ VT,
                                                const float* __restrict__ maskbias,
                                                u16* __restrict__ O0, u16* __restrict__ O1,
                                                float* __restrict__ Ms, float* __restrict__ Ss) {
  const int T = 2048;
  int bh = blockIdx.x;
  int qt = blockIdx.y;
  int sp = blockIdx.z;
  int b = bh >> 4;
  const u16* Qh = Q  + (size_t)bh * T * 64;
  const u16* Kh = Kg + (size_t)bh * T * 64;
  const u16* Vh = VT + (size_t)bh * T * 64;
  u16* Oh = (sp ? O1 : O0) + (size_t)bh * T * 64;
  const float* mb = maskbias + b * T + sp * 1024;
  int tid = threadIdx.x, w = tid >> 6, l = tid & 63;
  int q32 = l & 31, h = l >> 5;
  int qbase = qt * 128 + w * 32;
  const float C = 0.125f * LOG2E;

  __shared__ u16 Ks[2][4096];
  __shared__ u16 Vs[2][4096];

  bf16x8 qf[4];
#pragma unroll
  for (int dc = 0; dc < 4; dc++)
    qf[dc] = *(const bf16x8*)(Qh + (size_t)(qbase + q32) * 64 + dc * 16 + h * 8);

  int rl = l >> 3, ob = (l & 7) * 16;
  int osw = ob ^ (rl << 4);
  int r0 = w * 16 + rl, r1 = w * 16 + 8 + rl;
  const u16* pK0 = Kh + (size_t)(sp * 1024 + r0) * 64 + (osw >> 1);
  const u16* pK1 = Kh + (size_t)(sp * 1024 + r1) * 64 + (osw >> 1);
  const u16* pV0 = Vh + (size_t)r0 * 2048 + sp * 1024 + (osw >> 1);
  const u16* pV1 = Vh + (size_t)r1 * 2048 + sp * 1024 + (osw >> 1);
  u16* dK0 = &Ks[0][0] + (w * 16) * 64;
  u16* dK1 = &Ks[0][0] + (w * 16 + 8) * 64;
  u16* dV0 = &Vs[0][0] + (w * 16) * 64;
  u16* dV1 = &Vs[0][0] + (w * 16 + 8) * 64;

  auto stage = [&](int buf) {
    gload_lds16(pK0, dK0 + buf * 4096);
    gload_lds16(pK1, dK1 + buf * 4096);
    gload_lds16(pV0, dV0 + buf * 4096);
    gload_lds16(pV1, dV1 + buf * 4096);
    pK0 += 4096; pK1 += 4096; pV0 += 64; pV1 += 64;
  };

  f32x16 acc[2];
  acc[0] = (f32x16)0.0f; acc[1] = (f32x16)0.0f;
  float m_ = -3e30f, s_ = 0.0f;

  int swz = (q32 & 7) << 4;

  stage(0);
  for (int t = 0; t < 16; t++) {
    int cur = t & 1;
    __syncthreads();
    if (t < 15) stage(cur ^ 1);
    const char* ksb = (const char*)(&Ks[0][0] + cur * 4096);
    const char* vsb = (const char*)(&Vs[0][0] + cur * 4096);

    bf16x8 kf[2][4];
#pragma unroll
    for (int kvc = 0; kvc < 2; kvc++)
#pragma unroll
      for (int dc = 0; dc < 4; dc++)
        kf[kvc][dc] = *(const bf16x8*)(ksb + (kvc * 32 + q32) * 128 + ((dc * 32 + h * 16) ^ swz));

    f32x16 st[2];
    st[0] = (f32x16)0.0f; st[1] = (f32x16)0.0f;
    __builtin_amdgcn_s_setprio(1);
#pragma unroll
    for (int kvc = 0; kvc < 2; kvc++)
#pragma unroll
      for (int dc = 0; dc < 4; dc++)
        st[kvc] = __builtin_amdgcn_mfma_f32_32x32x16_bf16(kf[kvc][dc], qf[dc], st[kvc], 0, 0, 0);
    __builtin_amdgcn_s_setprio(0);

    float p[32];
#pragma unroll
    for (int kvc = 0; kvc < 2; kvc++) {
#pragma unroll
      for (int g = 0; g < 4; g++) {
        f32x4 mv = *(const f32x4*)(mb + t * 64 + kvc * 32 + g * 8 + h * 4);
#pragma unroll
        for (int r = 0; r < 4; r++)
          p[kvc * 16 + g * 4 + r] = st[kvc][g * 4 + r] * C + mv[r];
      }
    }
    // lane-local max via two max3 chains, then permlane cross-half
    float ma = p[0], mb2 = p[16];
#pragma unroll
    for (int i = 0; i < 7; i++) {
      ma  = max3f(ma,  p[1 + 2 * i],  p[2 + 2 * i]);
      mb2 = max3f(mb2, p[17 + 2 * i], p[18 + 2 * i]);
    }
    ma = fmaxf(ma, p[15]); mb2 = fmaxf(mb2, p[31]);
    float pmax = fmaxf(ma, mb2);
    i32x2 pr = __builtin_amdgcn_permlane32_swap(__float_as_int(pmax), __float_as_int(pmax), false, false);
    pmax = fmaxf(__int_as_float(pr[0]), __int_as_float(pr[1]));

    if (__any(pmax - m_ > 8.0f)) {
      float mnew = fmaxf(m_, pmax);
      float fsc = __builtin_amdgcn_exp2f(m_ - mnew);
      s_ *= fsc;
      m_ = mnew;
#pragma unroll
      for (int g = 0; g < 4; g++)
#pragma unroll
        for (int r = 0; r < 4; r++) {
          float f = __shfl(fsc, g * 8 + h * 4 + r);
          acc[0][g * 4 + r] *= f;
          acc[1][g * 4 + r] *= f;
        }
    }

    float rsum = 0.0f;
    u32 wds[16];
#pragma unroll
    for (int i = 0; i < 16; i++) {
      float a = __builtin_amdgcn_exp2f(p[2 * i] - m_);
      float bq = __builtin_amdgcn_exp2f(p[2 * i + 1] - m_);
      rsum += a + bq;
      union { __bf16 h2[2]; u32 u; } cv;
      cv.h2[0] = (__bf16)a; cv.h2[1] = (__bf16)bq;
      wds[i] = cv.u;
    }
    i32x2 sr = __builtin_amdgcn_permlane32_swap(__float_as_int(rsum), __float_as_int(rsum), false, false);
    rsum = __int_as_float(sr[0]) + __int_as_float(sr[1]);
    s_ += rsum;

#pragma unroll
    for (int kvc = 0; kvc < 2; kvc++) {
      int bse = kvc * 8;
      i32x2 r02 = __builtin_amdgcn_permlane32_swap((int)wds[bse + 0], (int)wds[bse + 2], false, false);
      i32x2 r13 = __builtin_amdgcn_permlane32_swap((int)wds[bse + 1], (int)wds[bse + 3], false, false);
      i32x2 r46 = __builtin_amdgcn_permlane32_swap((int)wds[bse + 4], (int)wds[bse + 6], false, false);
      i32x2 r57 = __builtin_amdgcn_permlane32_swap((int)wds[bse + 5], (int)wds[bse + 7], false, false);
      union { u32 u[4]; bf16x8 v; } pa0, pa1;
      pa0.u[0] = (u32)r02[0]; pa0.u[1] = (u32)r13[0]; pa0.u[2] = (u32)r02[1]; pa0.u[3] = (u32)r13[1];
      pa1.u[0] = (u32)r46[0]; pa1.u[1] = (u32)r57[0]; pa1.u[2] = (u32)r46[1]; pa1.u[3] = (u32)r57[1];
      __builtin_amdgcn_s_setprio(1);
#pragma unroll
      for (int cl = 0; cl < 2; cl++) {
        bf16x8 pa = cl ? pa1.v : pa0.v;
        int cg = kvc * 2 + cl;
#pragma unroll
        for (int dblk = 0; dblk < 2; dblk++) {
          bf16x8 vf = *(const bf16x8*)(vsb + (dblk * 32 + q32) * 128 + ((cg * 32 + h * 16) ^ swz));
          acc[dblk] = __builtin_amdgcn_mfma_f32_32x32x16_bf16(pa, vf, acc[dblk], 0, 0, 0);
        }
      }
      __builtin_amdgcn_s_setprio(0);
    }
  }

#pragma unroll
  for (int g = 0; g < 4; g++) {
#pragma unroll
    for (int r = 0; r < 4; r++) {
      int row = g * 8 + h * 4 + r;
#pragma unroll
      for (int dblk = 0; dblk < 2; dblk++)
        Oh[(size_t)(qbase + row) * 64 + dblk * 32 + q32] = f2bf(acc[dblk][g * 4 + r]);
    }
  }
  if (h == 0) {
    int ro = sp * 65536 + bh * 2048 + qbase + q32;
    Ms[ro] = m_;
    Ss[ro] = s_;
  }
}

// ---------------- split-KV combine (2 splits) ----------------
__global__ __launch_bounds__(256) void attn_combine(const u16* __restrict__ O0, const u16* __restrict__ O1,
                                                    const float* __restrict__ Ms, const float* __restrict__ Ss,
                                                    const float* __restrict__ qmaskf, u16* __restrict__ out) {
  int idx = blockIdx.x * 256 + threadIdx.x;
  int row = idx >> 3;
  int d8 = (idx & 7) * 8;
  int bh = row >> 11, r = row & 2047, b = bh >> 4;
  float m0 = Ms[row], m1 = Ms[65536 + row];
  float mstar = fmaxf(m0, m1);
  float w0 = __builtin_amdgcn_exp2f(m0 - mstar);
  float w1 = __builtin_amdgcn_exp2f(m1 - mstar);
  float den = w0 * Ss[row] + w1 * Ss[65536 + row];
  float scale = qmaskf[b * 2048 + r] / den;
  size_t base = (size_t)row * 64 + d8;
  u16x8 a0 = *(const u16x8*)(O0 + base);
  u16x8 a1 = *(const u16x8*)(O1 + base);
  u16x8 o;
#pragma unroll
  for (int e = 0; e < 8; e++)
    o[e] = f2bf((w0 * bf2f(a0[e]) + w1 * bf2f(a1[e])) * scale);
  *(u16x8*)(out + base) = o;
}

// ---------------- residual + split-K partial sum + (bias) + layernorm ----------------
template<int NP, int A_F32, int ADD_BIAS, int OUT_F32>
__global__ __launch_bounds__(256) void add_ln_multi(const void* __restrict__ Ap,
                                                    const u16* __restrict__ P0, const u16* __restrict__ P1,
                                                    const u16* __restrict__ P2, const u16* __restrict__ P3,
                                                    const float* __restrict__ bias,
                                                    const float* __restrict__ g, const float* __restrict__ be,
                                                    void* __restrict__ outp) {
  int row = blockIdx.x, tid = threadIdx.x;
  int lane = tid & 63, wave = tid >> 6;
  size_t rb = (size_t)row * 1024;
  float x[4];
  if (A_F32) {
    f32x4 a = ((const f32x4*)((const float*)Ap + rb))[tid];
#pragma unroll
    for (int j = 0; j < 4; j++) x[j] = a[j];
  } else {
    u16x4 au = ((const u16x4*)((const u16*)Ap + rb))[tid];
#pragma unroll
    for (int j = 0; j < 4; j++) x[j] = bf2f(au[j]);
  }
  {
    u16x4 p = ((const u16x4*)(P0 + rb))[tid];
#pragma unroll
    for (int j = 0; j < 4; j++) x[j] += bf2f(p[j]);
  }
  if (NP > 1) {
    u16x4 p = ((const u16x4*)(P1 + rb))[tid];
#pragma unroll
    for (int j = 0; j < 4; j++) x[j] += bf2f(p[j]);
  }
  if (NP > 2) {
    u16x4 p = ((const u16x4*)(P2 + rb))[tid];
#pragma unroll
    for (int j = 0; j < 4; j++) x[j] += bf2f(p[j]);
  }
  if (NP > 3) {
    u16x4 p = ((const u16x4*)(P3 + rb))[tid];
#pragma unroll
    for (int j = 0; j < 4; j++) x[j] += bf2f(p[j]);
  }
  if (ADD_BIAS) {
    f32x4 bv = ((const f32x4*)bias)[tid];
#pragma unroll
    for (int j = 0; j < 4; j++) x[j] += bv[j];
  }
  float s = x[0] + x[1] + x[2] + x[3];
  float q = x[0] * x[0] + x[1] * x[1] + x[2] * x[2] + x[3] * x[3];
#pragma unroll
  for (int m = 1; m < 64; m <<= 1) { s += __shfl_xor(s, m); q += __shfl_xor(q, m); }
  __shared__ float rs[4], rq[4];
  if (lane == 0) { rs[wave] = s; rq[wave] = q; }
  __syncthreads();
  float S = rs[0] + rs[1] + rs[2] + rs[3];
  float Qq = rq[0] + rq[1] + rq[2] + rq[3];
  float mean = S * (1.0f / 1024.0f);
  float var = Qq * (1.0f / 1024.0f) - mean * mean;
  float rstd = rsqrtf(var + 1e-5f);
  if (OUT_F32) {
    f32x4 y;
#pragma unroll
    for (int j = 0; j < 4; j++) { int col = tid * 4 + j; y[j] = (x[j] - mean) * rstd * g[col] + be[col]; }
    ((f32x4*)((float*)outp + rb))[tid] = y;
  } else {
    u16x4 y;
#pragma unroll
    for (int j = 0; j < 4; j++) { int col = tid * 4 + j; y[j] = f2bf((x[j] - mean) * rstd * g[col] + be[col]); }
    ((u16x4*)((u16*)outp + rb))[tid] = y;
  }
}

// ---------------- launch ----------------
extern "C" void kernel_launch(void* const* d_in, const int* in_sizes, int n_in,
                              void* d_out, int out_size, void* d_ws, size_t ws_size,
                              hipStream_t stream) {
  const float* q   = (const float*)d_in[0];
  const float* k   = (const float*)d_in[1];
  const float* v   = (const float*)d_in[2];
  const void*  pad = d_in[3];
  const float* Wq  = (const float*)d_in[4];
  const float* Wk  = (const float*)d_in[5];
  const float* Wv  = (const float*)d_in[6];
  const float* Wo  = (const float*)d_in[7];
  const float* W1  = (const float*)d_in[8];
  const float* b1  = (const float*)d_in[9];
  const float* W2  = (const float*)d_in[10];
  const float* b2  = (const float*)d_in[11];
  const float* g1  = (const float*)d_in[12];
  const float* be1 = (const float*)d_in[13];
  const float* g2  = (const float*)d_in[14];
  const float* be2 = (const float*)d_in[15];
  float* out = (float*)d_out;
  char* ws = (char*)d_ws;
  const size_t MB = 1u << 20;

  u16* wq_b = (u16*)(ws + 0 * MB);
  u16* wk_b = (u16*)(ws + 2 * MB);
  u16* wv_b = (u16*)(ws + 4 * MB);
  u16* wo_b = (u16*)(ws + 6 * MB);
  u16* w1_b = (u16*)(ws + 8 * MB);
  u16* w2_b = (u16*)(ws + 16 * MB);
  u16* qb   = (u16*)(ws + 24 * MB);
  u16* kb   = (u16*)(ws + 32 * MB);
  u16* vb   = (u16*)(ws + 40 * MB);
  u16* Qb   = (u16*)(ws + 48 * MB);
  u16* Kb   = (u16*)(ws + 56 * MB);
  u16* Vb   = (u16*)(ws + 64 * MB);
  u16* VTb  = (u16*)(ws + 72 * MB);
  u16* hatt = (u16*)(ws + 80 * MB);
  // liveness overlays
  u16* Op0  = (u16*)(ws + 24 * MB);   // qb dead after QKV
  u16* Op1  = (u16*)(ws + 32 * MB);   // kb dead
  float* Ms = (float*)(ws + 88 * MB);
  float* Ss = (float*)(ws + 89 * MB);
  u16* WP   = (u16*)(ws + 40 * MB);   // Wo split-K partials x2 (vb,Qb dead): 40-56
  u16* h1b  = (u16*)(ws + 24 * MB);   // Op0 dead after combine
  u16* ff1  = (u16*)(ws + 32 * MB);   // Op1/WP/Kb dead after LN1: 32-64 (32 MB)
  u16* Fp   = (u16*)(ws + 64 * MB);   // FFN2 split-K partials x4: 64-96
  float* maskbias = (float*)(ws + 96 * MB);
  float* qmaskf   = (float*)(ws + 96 * MB + 16384);

  build_masks<<<1, 256, 0, stream>>>(pad, maskbias, qmaskf, in_sizes[3]);

  cvt_all<<<24576, 256, 0, stream>>>(q, k, v, Wq, Wk, Wv, Wo, W1, W2,
                                     qb, kb, vb, wq_b, wk_b, wv_b, wo_b, w1_b, w2_b);

  gemm_qkv<<<dim3(8, 32, 3), 512, 0, stream>>>(qb, kb, vb, wq_b, wk_b, wv_b, Qb, Kb, Vb);

  transpose64<<<dim3(32, 32), 256, 0, stream>>>(Vb, VTb);

  attn4<<<dim3(32, 16, 2), 256, 0, stream>>>(Qb, Kb, VTb, maskbias, Op0, Op1, Ms, Ss);

  attn_combine<<<2048, 256, 0, stream>>>(Op0, Op1, Ms, Ss, qmaskf, hatt);

  // Wo: split-K x2 (Kc=512), partials -> WP[2][4096][1024]
  gemm_splitk<<<dim3(8, 32, 2), 512, 0, stream>>>(hatt, wo_b, WP, 1024, 1024, 512);

  // LN1: q + WP0 + WP1 -> h1b (bf16)
  add_ln_multi<2, 1, 0, 0><<<4096, 256, 0, stream>>>(q, WP, WP + 4194304, nullptr, nullptr,
                                                     nullptr, g1, be1, h1b);

  // FFN1: h1 @ W1^T + b1, GELU -> ff1
  gemm_bt<2><<<dim3(32, 32), 512, 0, stream>>>(h1b, w1_b, b1, ff1, 4096, 1024);

  // FFN2: split-K x4 (Kc=1024), partials -> Fp[4][4096][1024]
  gemm_splitk<<<dim3(8, 32, 4), 512, 0, stream>>>(ff1, w2_b, Fp, 1024, 4096, 1024);

  // LN2: h1 + sum(Fp) + b2 -> out (f32)
  add_ln_multi<4, 0, 1, 1><<<4096, 256, 0, stream>>>(h1b, Fp, Fp + 4194304, Fp + 2 * 4194304,
                                                     Fp + 3 * 4194304, b2, g2, be2, out);
}

// Round 16
// 272.496 us; speedup vs baseline: 1.2545x; 1.0012x over previous
//
#include <hip/hip_runtime.h>

typedef unsigned short u16;
typedef unsigned int u32;
typedef __attribute__((ext_vector_type(8))) __bf16 bf16x8;
typedef __attribute__((ext_vector_type(4))) float f32x4;
typedef __attribute__((ext_vector_type(16))) float f32x16;
typedef __attribute__((ext_vector_type(4))) unsigned short u16x4;
typedef __attribute__((ext_vector_type(8))) unsigned short u16x8;
typedef __attribute__((ext_vector_type(2))) int i32x2;

#define LOG2E 1.44269504088896340736f

__device__ __forceinline__ u16 f2bf(float f) {
  union { float f; unsigned u; } c; c.f = f;
  unsigned r = c.u + 0x7FFFu + ((c.u >> 16) & 1u);
  return (u16)(r >> 16);
}
__device__ __forceinline__ float bf2f(u16 h) {
  union { unsigned u; float f; } c; c.u = ((unsigned)h) << 16;
  return c.f;
}
__device__ __forceinline__ float max3f(float a, float b, float c) {
  return fmaxf(fmaxf(a, b), c);
}

__device__ __forceinline__ void gload_lds16(const u16* g, u16* l) {
  __builtin_amdgcn_global_load_lds((const __attribute__((address_space(1))) unsigned int*)g,
                                   (__attribute__((address_space(3))) unsigned int*)l, 16, 0, 0);
}

// fast exact GELU: erf via Abramowitz-Stegun 7.1.26 (|eps| <= 1.5e-7)
__device__ __forceinline__ float gelu_fast(float x) {
  float z = fabsf(x) * 0.70710678118654752f;
  float t = 1.0f / (1.0f + 0.3275911f * z);
  float poly = t * (0.254829592f + t * (-0.284496736f + t * (1.421413741f +
               t * (-1.453152027f + t * 1.061405429f))));
  float e = __builtin_amdgcn_exp2f(-z * z * LOG2E);
  float erfz = 1.0f - poly * e;
  float s = (x >= 0.0f) ? erfz : -erfz;
  return 0.5f * x * (1.0f + s);
}

// ---------------- fused f32 -> bf16 conversion (all 9 tensors, one launch) ----------------
__global__ __launch_bounds__(256) void cvt_all(
    const float* __restrict__ s0, const float* __restrict__ s1, const float* __restrict__ s2,
    const float* __restrict__ s3, const float* __restrict__ s4, const float* __restrict__ s5,
    const float* __restrict__ s6, const float* __restrict__ s7, const float* __restrict__ s8,
    u16* __restrict__ d0, u16* __restrict__ d1, u16* __restrict__ d2,
    u16* __restrict__ d3, u16* __restrict__ d4, u16* __restrict__ d5,
    u16* __restrict__ d6, u16* __restrict__ d7, u16* __restrict__ d8) {
  int i = blockIdx.x * 256 + threadIdx.x;
  if (i >= 6291456) return;
  const float* src; u16* dst; int off;
  if (i < 3145728) {
    if (i < 1048576)      { src = s0; dst = d0; off = 0; }
    else if (i < 2097152) { src = s1; dst = d1; off = 1048576; }
    else                  { src = s2; dst = d2; off = 2097152; }
  } else if (i < 4194304) {
    if (i < 3407872)      { src = s3; dst = d3; off = 3145728; }
    else if (i < 3670016) { src = s4; dst = d4; off = 3407872; }
    else if (i < 3932160) { src = s5; dst = d5; off = 3670016; }
    else                  { src = s6; dst = d6; off = 3932160; }
  } else {
    if (i < 5242880)      { src = s7; dst = d7; off = 4194304; }
    else                  { src = s8; dst = d8; off = 5242880; }
  }
  int j = i - off;
  f32x4 v = ((const f32x4*)src)[j];
  u16x4 o;
  o[0] = f2bf(v[0]); o[1] = f2bf(v[1]); o[2] = f2bf(v[2]); o[3] = f2bf(v[3]);
  ((u16x4*)dst)[j] = o;
}

// ---------------- mask expansion (bool/int32 autodetect) ----------------
__global__ void build_masks(const void* __restrict__ pm, float* __restrict__ maskbias,
                            float* __restrict__ qmask, int n) {
  __shared__ int sflag;
  if (threadIdx.x == 0) sflag = 0;
  __syncthreads();
  const unsigned* pw = (const unsigned*)pm;
  int nwords = n / 4;
  int local = 0;
  for (int i = threadIdx.x; i < nwords; i += blockDim.x)
    if (pw[i] > 1u) local = 1;
  if (local) atomicOr(&sflag, 1);
  __syncthreads();
  bool isbool = (sflag != 0);
  for (int i = threadIdx.x; i < n; i += blockDim.x) {
    int m = isbool ? (int)((const unsigned char*)pm)[i] : ((const int*)pm)[i];
    maskbias[i] = m ? 0.0f : -2e30f;
    qmask[i]    = m ? 1.0f : 0.0f;
  }
}

// ---------------- GEMM core v5: BK=64, swizzled LDS (2-way-free), 1 barrier/phase ----------
// C[M,N] = act(A[M,Klen] @ W[N,Klen]^T + bias) -> bf16.  512 threads/block, 64KB LDS.
template<int EPI>
__device__ __forceinline__ void gemm_core(const u16* __restrict__ A, const u16* __restrict__ Bw,
                                          const float* __restrict__ bias, u16* __restrict__ C,
                                          int N, int Kstride, int Klen, int bn, int bm, int tid) {
  __shared__ u16 smem[2][16384];   // [buf][ A 0..8191 | B 8192..16383 ]  64 KB
  int wave = tid >> 6, lane = tid & 63;
  int l15 = lane & 15, l4 = lane >> 4;
  int wr = (wave >> 1) * 32;       // 4 wave-rows over 128
  int wc = (wave & 1) * 64;        // 2 wave-cols over 128
  int mrow0 = bm * 128, ncol0 = bn * 128;
  int rl = lane >> 3;                         // sub-row 0..7
  int osw = ((lane & 7) * 16) ^ (rl << 4);    // swizzled byte offset in 128B row
  int oswe = osw >> 1;                        // elements

  const u16* asrc0 = A  + (size_t)(mrow0 + wave * 16 + rl) * Kstride + oswe;
  const u16* asrc1 = A  + (size_t)(mrow0 + wave * 16 + 8 + rl) * Kstride + oswe;
  const u16* bsrc0 = Bw + (size_t)(ncol0 + wave * 16 + rl) * Kstride + oswe;
  const u16* bsrc1 = Bw + (size_t)(ncol0 + wave * 16 + 8 + rl) * Kstride + oswe;
  u16* adst0 = &smem[0][wave * 1024];
  u16* adst1 = &smem[0][wave * 1024 + 512];
  u16* bdst0 = &smem[0][8192 + wave * 1024];
  u16* bdst1 = &smem[0][8192 + wave * 1024 + 512];

  auto stage = [&](int buf, int k0) {
    gload_lds16(asrc0 + k0, adst0 + buf * 16384);
    gload_lds16(asrc1 + k0, adst1 + buf * 16384);
    gload_lds16(bsrc0 + k0, bdst0 + buf * 16384);
    gload_lds16(bsrc1 + k0, bdst1 + buf * 16384);
  };

  f32x4 acc[2][4];
#pragma unroll
  for (int i = 0; i < 2; i++)
#pragma unroll
    for (int j = 0; j < 4; j++) acc[i][j] = (f32x4)0.0f;

  int nsteps = Klen >> 6;
  stage(0, 0);
  int swzr = (l15 & 7) << 4;
  for (int s = 0; s < nsteps; s++) {
    asm volatile("s_waitcnt vmcnt(0)" ::: "memory");  // tile s landed (flew during phase s-1)
    __builtin_amdgcn_s_barrier();
    if (s + 1 < nsteps) stage((s + 1) & 1, (s + 1) << 6);  // issue-early, lands during this phase
    const char* as = (const char*)&smem[s & 1][0];
    const char* bs = (const char*)&smem[s & 1][8192];
#pragma unroll
    for (int kk = 0; kk < 2; kk++) {
      bf16x8 af[2], bfr[4];
#pragma unroll
      for (int mi = 0; mi < 2; mi++)
        af[mi]  = *(const bf16x8*)(as + (wr + mi * 16 + l15) * 128 + ((kk * 64 + l4 * 16) ^ swzr));
#pragma unroll
      for (int ni = 0; ni < 4; ni++)
        bfr[ni] = *(const bf16x8*)(bs + (wc + ni * 16 + l15) * 128 + ((kk * 64 + l4 * 16) ^ swzr));
#pragma unroll
      for (int mi = 0; mi < 2; mi++)
#pragma unroll
        for (int ni = 0; ni < 4; ni++)
          acc[mi][ni] = __builtin_amdgcn_mfma_f32_16x16x32_bf16(af[mi], bfr[ni], acc[mi][ni], 0, 0, 0);
    }
  }

  // epilogue: single-pass LDS bounce ([128][136] u16 = 34 KB) -> coalesced u16x8 stores
  __syncthreads();
  u16* ct = &smem[0][0];
#pragma unroll
  for (int ni = 0; ni < 4; ni++) {
    int gcol = ncol0 + wc + ni * 16 + l15;
    float bv = (EPI > 0) ? bias[gcol] : 0.0f;
#pragma unroll
    for (int mi = 0; mi < 2; mi++) {
#pragma unroll
      for (int r = 0; r < 4; r++) {
        float v = acc[mi][ni][r] + bv;
        if (EPI == 2) v = gelu_fast(v);
        ct[(wr + mi * 16 + l4 * 4 + r) * 136 + wc + ni * 16 + l15] = f2bf(v);
      }
    }
  }
  __syncthreads();
  int lrow = tid >> 2, cq = tid & 3;
#pragma unroll
  for (int j = 0; j < 4; j++) {
    int col = cq * 8 + j * 32;
    u16x8 vv = *(const u16x8*)(ct + lrow * 136 + col);
    *(u16x8*)(C + (size_t)(mrow0 + lrow) * N + ncol0 + col) = vv;
  }
}

template<int EPI>
__global__ __launch_bounds__(512, 4) void gemm_bt(const u16* __restrict__ A, const u16* __restrict__ Bw,
                                                  const float* __restrict__ bias, u16* __restrict__ C,
                                                  int N, int K) {
  gemm_core<EPI>(A, Bw, bias, C, N, K, K, blockIdx.x, blockIdx.y, threadIdx.x);
}

// split-K GEMM: blockIdx.z selects K-chunk of length Kc; writes bf16 partial at P + z*M*N
__global__ __launch_bounds__(512, 4) void gemm_splitk(const u16* __restrict__ A, const u16* __restrict__ Bw,
                                                      u16* __restrict__ P, int N, int Kstride, int Kc) {
  int z = blockIdx.z;
  size_t M = (size_t)gridDim.y * 128;
  gemm_core<0>(A + (size_t)z * Kc, Bw + (size_t)z * Kc, nullptr,
               P + (size_t)z * M * N, N, Kstride, Kc, blockIdx.x, blockIdx.y, threadIdx.x);
}

__global__ __launch_bounds__(512, 4) void gemm_qkv(const u16* __restrict__ qb, const u16* __restrict__ kb,
                                                   const u16* __restrict__ vb,
                                                   const u16* __restrict__ wq, const u16* __restrict__ wk,
                                                   const u16* __restrict__ wv,
                                                   u16* __restrict__ Qo, u16* __restrict__ Ko, u16* __restrict__ Vo) {
  const u16* A; const u16* W; u16* C;
  if (blockIdx.z == 0)      { A = qb; W = wq; C = Qo; }
  else if (blockIdx.z == 1) { A = kb; W = wk; C = Ko; }
  else                      { A = vb; W = wv; C = Vo; }
  gemm_core<0>(A, W, nullptr, C, 1024, 1024, 1024, blockIdx.x, blockIdx.y, threadIdx.x);
}

// ---------------- V transpose: [32][2048][64] -> [32][64][2048] ----------------
// (contiguous head reinterpretation per torch .view; fused transposed GEMM store would be
//  stride-32B u32-grain scattered -> 8x write amplification, worse than this kernel)
__global__ __launch_bounds__(256) void transpose64(const u16* __restrict__ in, u16* __restrict__ out) {
  int bh = blockIdx.y, tb = blockIdx.x;
  __shared__ u16 tile[64 * 72];
  int tid = threadIdx.x;
#pragma unroll
  for (int it = 0; it < 2; it++) {
    int idx = it * 256 + tid;
    int r = idx >> 3, c8 = (idx & 7) * 8;
    u16x8 v = *(const u16x8*)(in + ((size_t)bh * 2048 + tb * 64 + r) * 64 + c8);
    int byte = ((r * 72 + c8) * 2) ^ (((r >> 3) & 7) << 4);
    *(u16x8*)((char*)tile + byte) = v;
  }
  __syncthreads();
#pragma unroll
  for (int it = 0; it < 2; it++) {
    int idx = it * 256 + tid;
    int d = idx >> 3, t8 = (idx & 7) * 8;
    u16x8 o;
#pragma unroll
    for (int e = 0; e < 8; e++) {
      int t = t8 + e;
      int byte = ((t * 72 + d) * 2) ^ (((t >> 3) & 7) << 4);
      o[e] = *(const u16*)((const char*)tile + byte);
    }
    *(u16x8*)(out + ((size_t)bh * 64 + d) * 2048 + tb * 64 + t8) = o;
  }
}

// ---------------- flash attention v5 (round-9 exact): LDS K/V, swapped-QK, permlane softmax
__global__ __launch_bounds__(256, 4) void attn4(const u16* __restrict__ Q, const u16* __restrict__ Kg,
                                                const u16* __restrict__ VT,
                                                const float* __restrict__ maskbias,
                                                u16* __restrict__ O0, u16* __restrict__ O1,
                                                float* __restrict__ Ms, float* __restrict__ Ss) {
  const int T = 2048;
  int bh = blockIdx.x;
  int qt = blockIdx.y;
  int sp = blockIdx.z;
  int b = bh >> 4;
  const u16* Qh = Q  + (size_t)bh * T * 64;
  const u16* Kh = Kg + (size_t)bh * T * 64;
  const u16* Vh = VT + (size_t)bh * T * 64;
  u16* Oh = (sp ? O1 : O0) + (size_t)bh * T * 64;
  const float* mb = maskbias + b * T + sp * 1024;
  int tid = threadIdx.x, w = tid >> 6, l = tid & 63;
  int q32 = l & 31, h = l >> 5;
  int qbase = qt * 128 + w * 32;
  const float C = 0.125f * LOG2E;

  __shared__ u16 Ks[2][4096];
  __shared__ u16 Vs[2][4096];

  bf16x8 qf[4];
#pragma unroll
  for (int dc = 0; dc < 4; dc++)
    qf[dc] = *(const bf16x8*)(Qh + (size_t)(qbase + q32) * 64 + dc * 16 + h * 8);

  int rl = l >> 3, ob = (l & 7) * 16;
  int osw = ob ^ (rl << 4);
  int r0 = w * 16 + rl, r1 = w * 16 + 8 + rl;
  const u16* pK0 = Kh + (size_t)(sp * 1024 + r0) * 64 + (osw >> 1);
  const u16* pK1 = Kh + (size_t)(sp * 1024 + r1) * 64 + (osw >> 1);
  const u16* pV0 = Vh + (size_t)r0 * 2048 + sp * 1024 + (osw >> 1);
  const u16* pV1 = Vh + (size_t)r1 * 2048 + sp * 1024 + (osw >> 1);
  u16* dK0 = &Ks[0][0] + (w * 16) * 64;
  u16* dK1 = &Ks[0][0] + (w * 16 + 8) * 64;
  u16* dV0 = &Vs[0][0] + (w * 16) * 64;
  u16* dV1 = &Vs[0][0] + (w * 16 + 8) * 64;

  auto stage = [&](int buf) {
    gload_lds16(pK0, dK0 + buf * 4096);
    gload_lds16(pK1, dK1 + buf * 4096);
    gload_lds16(pV0, dV0 + buf * 4096);
    gload_lds16(pV1, dV1 + buf * 4096);
    pK0 += 4096; pK1 += 4096; pV0 += 64; pV1 += 64;
  };

  f32x16 acc[2];
  acc[0] = (f32x16)0.0f; acc[1] = (f32x16)0.0f;
  float m_ = -3e30f, s_ = 0.0f;

  int swz = (q32 & 7) << 4;

  stage(0);
  for (int t = 0; t < 16; t++) {
    int cur = t & 1;
    __syncthreads();
    if (t < 15) stage(cur ^ 1);
    const char* ksb = (const char*)(&Ks[0][0] + cur * 4096);
    const char* vsb = (const char*)(&Vs[0][0] + cur * 4096);

    bf16x8 kf[2][4];
#pragma unroll
    for (int kvc = 0; kvc < 2; kvc++)
#pragma unroll
      for (int dc = 0; dc < 4; dc++)
        kf[kvc][dc] = *(const bf16x8*)(ksb + (kvc * 32 + q32) * 128 + ((dc * 32 + h * 16) ^ swz));

    f32x16 st[2];
    st[0] = (f32x16)0.0f; st[1] = (f32x16)0.0f;
#pragma unroll
    for (int kvc = 0; kvc < 2; kvc++)
#pragma unroll
      for (int dc = 0; dc < 4; dc++)
        st[kvc] = __builtin_amdgcn_mfma_f32_32x32x16_bf16(kf[kvc][dc], qf[dc], st[kvc], 0, 0, 0);

    float p[32];
#pragma unroll
    for (int kvc = 0; kvc < 2; kvc++) {
#pragma unroll
      for (int g = 0; g < 4; g++) {
        f32x4 mv = *(const f32x4*)(mb + t * 64 + kvc * 32 + g * 8 + h * 4);
#pragma unroll
        for (int r = 0; r < 4; r++)
          p[kvc * 16 + g * 4 + r] = st[kvc][g * 4 + r] * C + mv[r];
      }
    }
    // lane-local max via two max3 chains, then permlane cross-half
    float ma = p[0], mb2 = p[16];
#pragma unroll
    for (int i = 0; i < 7; i++) {
      ma  = max3f(ma,  p[1 + 2 * i],  p[2 + 2 * i]);
      mb2 = max3f(mb2, p[17 + 2 * i], p[18 + 2 * i]);
    }
    ma = fmaxf(ma, p[15]); mb2 = fmaxf(mb2, p[31]);
    float pmax = fmaxf(ma, mb2);
    i32x2 pr = __builtin_amdgcn_permlane32_swap(__float_as_int(pmax), __float_as_int(pmax), false, false);
    pmax = fmaxf(__int_as_float(pr[0]), __int_as_float(pr[1]));

    if (__any(pmax - m_ > 8.0f)) {
      float mnew = fmaxf(m_, pmax);
      float fsc = __builtin_amdgcn_exp2f(m_ - mnew);
      s_ *= fsc;
      m_ = mnew;
#pragma unroll
      for (int g = 0; g < 4; g++)
#pragma unroll
        for (int r = 0; r < 4; r++) {
          float f = __shfl(fsc, g * 8 + h * 4 + r);
          acc[0][g * 4 + r] *= f;
          acc[1][g * 4 + r] *= f;
        }
    }

    float rsum = 0.0f;
    u32 wds[16];
#pragma unroll
    for (int i = 0; i < 16; i++) {
      float a = __builtin_amdgcn_exp2f(p[2 * i] - m_);
      float bq = __builtin_amdgcn_exp2f(p[2 * i + 1] - m_);
      rsum += a + bq;
      union { __bf16 h2[2]; u32 u; } cv;
      cv.h2[0] = (__bf16)a; cv.h2[1] = (__bf16)bq;
      wds[i] = cv.u;
    }
    i32x2 sr = __builtin_amdgcn_permlane32_swap(__float_as_int(rsum), __float_as_int(rsum), false, false);
    rsum = __int_as_float(sr[0]) + __int_as_float(sr[1]);
    s_ += rsum;

#pragma unroll
    for (int kvc = 0; kvc < 2; kvc++) {
      int bse = kvc * 8;
      i32x2 r02 = __builtin_amdgcn_permlane32_swap((int)wds[bse + 0], (int)wds[bse + 2], false, false);
      i32x2 r13 = __builtin_amdgcn_permlane32_swap((int)wds[bse + 1], (int)wds[bse + 3], false, false);
      i32x2 r46 = __builtin_amdgcn_permlane32_swap((int)wds[bse + 4], (int)wds[bse + 6], false, false);
      i32x2 r57 = __builtin_amdgcn_permlane32_swap((int)wds[bse + 5], (int)wds[bse + 7], false, false);
      union { u32 u[4]; bf16x8 v; } pa0, pa1;
      pa0.u[0] = (u32)r02[0]; pa0.u[1] = (u32)r13[0]; pa0.u[2] = (u32)r02[1]; pa0.u[3] = (u32)r13[1];
      pa1.u[0] = (u32)r46[0]; pa1.u[1] = (u32)r57[0]; pa1.u[2] = (u32)r46[1]; pa1.u[3] = (u32)r57[1];
#pragma unroll
      for (int cl = 0; cl < 2; cl++) {
        bf16x8 pa = cl ? pa1.v : pa0.v;
        int cg = kvc * 2 + cl;
#pragma unroll
        for (int dblk = 0; dblk < 2; dblk++) {
          bf16x8 vf = *(const bf16x8*)(vsb + (dblk * 32 + q32) * 128 + ((cg * 32 + h * 16) ^ swz));
          acc[dblk] = __builtin_amdgcn_mfma_f32_32x32x16_bf16(pa, vf, acc[dblk], 0, 0, 0);
        }
      }
    }
  }

#pragma unroll
  for (int g = 0; g < 4; g++) {
#pragma unroll
    for (int r = 0; r < 4; r++) {
      int row = g * 8 + h * 4 + r;
#pragma unroll
      for (int dblk = 0; dblk < 2; dblk++)
        Oh[(size_t)(qbase + row) * 64 + dblk * 32 + q32] = f2bf(acc[dblk][g * 4 + r]);
    }
  }
  if (h == 0) {
    int ro = sp * 65536 + bh * 2048 + qbase + q32;
    Ms[ro] = m_;
    Ss[ro] = s_;
  }
}

// ---------------- split-KV combine (2 splits) ----------------
__global__ __launch_bounds__(256) void attn_combine(const u16* __restrict__ O0, const u16* __restrict__ O1,
                                                    const float* __restrict__ Ms, const float* __restrict__ Ss,
                                                    const float* __restrict__ qmaskf, u16* __restrict__ out) {
  int idx = blockIdx.x * 256 + threadIdx.x;
  int row = idx >> 3;
  int d8 = (idx & 7) * 8;
  int bh = row >> 11, r = row & 2047, b = bh >> 4;
  float m0 = Ms[row], m1 = Ms[65536 + row];
  float mstar = fmaxf(m0, m1);
  float w0 = __builtin_amdgcn_exp2f(m0 - mstar);
  float w1 = __builtin_amdgcn_exp2f(m1 - mstar);
  float den = w0 * Ss[row] + w1 * Ss[65536 + row];
  float scale = qmaskf[b * 2048 + r] / den;
  size_t base = (size_t)row * 64 + d8;
  u16x8 a0 = *(const u16x8*)(O0 + base);
  u16x8 a1 = *(const u16x8*)(O1 + base);
  u16x8 o;
#pragma unroll
  for (int e = 0; e < 8; e++)
    o[e] = f2bf((w0 * bf2f(a0[e]) + w1 * bf2f(a1[e])) * scale);
  *(u16x8*)(out + base) = o;
}

// ---------------- residual + split-K partial sum + (bias) + layernorm ----------------
template<int NP, int A_F32, int ADD_BIAS, int OUT_F32>
__global__ __launch_bounds__(256) void add_ln_multi(const void* __restrict__ Ap,
                                                    const u16* __restrict__ P0, const u16* __restrict__ P1,
                                                    const u16* __restrict__ P2, const u16* __restrict__ P3,
                                                    const float* __restrict__ bias,
                                                    const float* __restrict__ g, const float* __restrict__ be,
                                                    void* __restrict__ outp) {
  int row = blockIdx.x, tid = threadIdx.x;
  int lane = tid & 63, wave = tid >> 6;
  size_t rb = (size_t)row * 1024;
  float x[4];
  if (A_F32) {
    f32x4 a = ((const f32x4*)((const float*)Ap + rb))[tid];
#pragma unroll
    for (int j = 0; j < 4; j++) x[j] = a[j];
  } else {
    u16x4 au = ((const u16x4*)((const u16*)Ap + rb))[tid];
#pragma unroll
    for (int j = 0; j < 4; j++) x[j] = bf2f(au[j]);
  }
  {
    u16x4 p = ((const u16x4*)(P0 + rb))[tid];
#pragma unroll
    for (int j = 0; j < 4; j++) x[j] += bf2f(p[j]);
  }
  if (NP > 1) {
    u16x4 p = ((const u16x4*)(P1 + rb))[tid];
#pragma unroll
    for (int j = 0; j < 4; j++) x[j] += bf2f(p[j]);
  }
  if (NP > 2) {
    u16x4 p = ((const u16x4*)(P2 + rb))[tid];
#pragma unroll
    for (int j = 0; j < 4; j++) x[j] += bf2f(p[j]);
  }
  if (NP > 3) {
    u16x4 p = ((const u16x4*)(P3 + rb))[tid];
#pragma unroll
    for (int j = 0; j < 4; j++) x[j] += bf2f(p[j]);
  }
  if (ADD_BIAS) {
    f32x4 bv = ((const f32x4*)bias)[tid];
#pragma unroll
    for (int j = 0; j < 4; j++) x[j] += bv[j];
  }
  float s = x[0] + x[1] + x[2] + x[3];
  float q = x[0] * x[0] + x[1] * x[1] + x[2] * x[2] + x[3] * x[3];
#pragma unroll
  for (int m = 1; m < 64; m <<= 1) { s += __shfl_xor(s, m); q += __shfl_xor(q, m); }
  __shared__ float rs[4], rq[4];
  if (lane == 0) { rs[wave] = s; rq[wave] = q; }
  __syncthreads();
  float S = rs[0] + rs[1] + rs[2] + rs[3];
  float Qq = rq[0] + rq[1] + rq[2] + rq[3];
  float mean = S * (1.0f / 1024.0f);
  float var = Qq * (1.0f / 1024.0f) - mean * mean;
  float rstd = rsqrtf(var + 1e-5f);
  if (OUT_F32) {
    f32x4 y;
#pragma unroll
    for (int j = 0; j < 4; j++) { int col = tid * 4 + j; y[j] = (x[j] - mean) * rstd * g[col] + be[col]; }
    ((f32x4*)((float*)outp + rb))[tid] = y;
  } else {
    u16x4 y;
#pragma unroll
    for (int j = 0; j < 4; j++) { int col = tid * 4 + j; y[j] = f2bf((x[j] - mean) * rstd * g[col] + be[col]); }
    ((u16x4*)((u16*)outp + rb))[tid] = y;
  }
}

// ---------------- launch ----------------
extern "C" void kernel_launch(void* const* d_in, const int* in_sizes, int n_in,
                              void* d_out, int out_size, void* d_ws, size_t ws_size,
                              hipStream_t stream) {
  const float* q   = (const float*)d_in[0];
  const float* k   = (const float*)d_in[1];
  const float* v   = (const float*)d_in[2];
  const void*  pad = d_in[3];
  const float* Wq  = (const float*)d_in[4];
  const float* Wk  = (const float*)d_in[5];
  const float* Wv  = (const float*)d_in[6];
  const float* Wo  = (const float*)d_in[7];
  const float* W1  = (const float*)d_in[8];
  const float* b1  = (const float*)d_in[9];
  const float* W2  = (const float*)d_in[10];
  const float* b2  = (const float*)d_in[11];
  const float* g1  = (const float*)d_in[12];
  const float* be1 = (const float*)d_in[13];
  const float* g2  = (const float*)d_in[14];
  const float* be2 = (const float*)d_in[15];
  float* out = (float*)d_out;
  char* ws = (char*)d_ws;
  const size_t MB = 1u << 20;

  u16* wq_b = (u16*)(ws + 0 * MB);
  u16* wk_b = (u16*)(ws + 2 * MB);
  u16* wv_b = (u16*)(ws + 4 * MB);
  u16* wo_b = (u16*)(ws + 6 * MB);
  u16* w1_b = (u16*)(ws + 8 * MB);
  u16* w2_b = (u16*)(ws + 16 * MB);
  u16* qb   = (u16*)(ws + 24 * MB);
  u16* kb   = (u16*)(ws + 32 * MB);
  u16* vb   = (u16*)(ws + 40 * MB);
  u16* Qb   = (u16*)(ws + 48 * MB);
  u16* Kb   = (u16*)(ws + 56 * MB);
  u16* Vb   = (u16*)(ws + 64 * MB);
  u16* VTb  = (u16*)(ws + 72 * MB);
  u16* hatt = (u16*)(ws + 80 * MB);
  // liveness overlays
  u16* Op0  = (u16*)(ws + 24 * MB);   // qb dead after QKV
  u16* Op1  = (u16*)(ws + 32 * MB);   // kb dead
  float* Ms = (float*)(ws + 88 * MB);
  float* Ss = (float*)(ws + 89 * MB);
  u16* WP   = (u16*)(ws + 40 * MB);   // Wo split-K partials x2 (vb,Qb dead): 40-56
  u16* h1b  = (u16*)(ws + 24 * MB);   // Op0 dead after combine
  u16* ff1  = (u16*)(ws + 32 * MB);   // Op1/WP/Kb dead after LN1: 32-64 (32 MB)
  u16* Fp   = (u16*)(ws + 64 * MB);   // FFN2 split-K partials x4: 64-96
  float* maskbias = (float*)(ws + 96 * MB);
  float* qmaskf   = (float*)(ws + 96 * MB + 16384);

  build_masks<<<1, 256, 0, stream>>>(pad, maskbias, qmaskf, in_sizes[3]);

  cvt_all<<<24576, 256, 0, stream>>>(q, k, v, Wq, Wk, Wv, Wo, W1, W2,
                                     qb, kb, vb, wq_b, wk_b, wv_b, wo_b, w1_b, w2_b);

  gemm_qkv<<<dim3(8, 32, 3), 512, 0, stream>>>(qb, kb, vb, wq_b, wk_b, wv_b, Qb, Kb, Vb);

  transpose64<<<dim3(32, 32), 256, 0, stream>>>(Vb, VTb);

  attn4<<<dim3(32, 16, 2), 256, 0, stream>>>(Qb, Kb, VTb, maskbias, Op0, Op1, Ms, Ss);

  attn_combine<<<2048, 256, 0, stream>>>(Op0, Op1, Ms, Ss, qmaskf, hatt);

  // Wo: split-K x2 (Kc=512), partials -> WP[2][4096][1024]
  gemm_splitk<<<dim3(8, 32, 2), 512, 0, stream>>>(hatt, wo_b, WP, 1024, 1024, 512);

  // LN1: q + WP0 + WP1 -> h1b (bf16)
  add_ln_multi<2, 1, 0, 0><<<4096, 256, 0, stream>>>(q, WP, WP + 4194304, nullptr, nullptr,
                                                     nullptr, g1, be1, h1b);

  // FFN1: h1 @ W1^T + b1, GELU -> ff1
  gemm_bt<2><<<dim3(32, 32), 512, 0, stream>>>(h1b, w1_b, b1, ff1, 4096, 1024);

  // FFN2: split-K x4 (Kc=1024), partials -> Fp[4][4096][1024]
  gemm_splitk<<<dim3(8, 32, 4), 512, 0, stream>>>(ff1, w2_b, Fp, 1024, 4096, 1024);

  // LN2: h1 + sum(Fp) + b2 -> out (f32)
  add_ln_multi<4, 0, 1, 1><<<4096, 256, 0, stream>>>(h1b, Fp, Fp + 4194304, Fp + 2 * 4194304,
                                                     Fp + 3 * 4194304, b2, g2, be2, out);
}